// Round 4
// baseline (20510.501 us; speedup 1.0000x reference)
//
#include <hip/hip_runtime.h>
#include <hip/hip_bf16.h>

// ============================================================================
// xLSTM audio model, fp32. B=4, S=1024, D=1024, INNER=2048, NH_M=4, DH_M=512,
// NH_S=4, DH_S=256, K(conv)=4, FF_UP=1344. N = B*S = 4096 tokens.
//
// R4 = R3 resubmit (R3 never ran: GPU acquisition timeout) + hardening:
//  - ex parity buffer correctly sized: 16 bh * 4 gates * 256 = 16384 floats
//    per parity (R2 bug: sized 4096 -> preact stores stomped flags -> hang).
//  - flag release/acquire made explicit (RELEASE fetch_add / ACQUIRE spin).
//  - spin bounded (cap 100k sleeps) so a protocol bug yields a wrong-result
//    fail instead of a harness-killing hang.
// ============================================================================

#define DEV_INLINE __device__ __forceinline__

constexpr long OFF_XN = 0;
constexpr long OFF_UP = 4l << 20;
constexpr long OFF_XC = 20l << 20;
constexpr long OFF_HS = 24l << 20;
constexpr long OFF_H  = 28l << 20;
constexpr long OFF_X1 = 36l << 20;
constexpr long OFF_SM = 40l << 20;

DEV_INLINE float wave_reduce_sum(float v) {
#pragma unroll
  for (int o = 32; o > 0; o >>= 1) v += __shfl_xor(v, o);
  return v;
}

DEV_INLINE float silu_f(float x) { return x / (1.f + expf(-x)); }
DEV_INLINE float selu_f(float x) {
  return 1.0507009873554805f * (x > 0.f ? x : 1.6732632423543772f * (expf(x) - 1.f));
}

// ---------------------------------------------------------------------------
// LayerNorm over D=1024 (one row per block, 256 threads), optional SELU.
// ---------------------------------------------------------------------------
__global__ __launch_bounds__(256) void ln1024_kernel(
    const float* __restrict__ in, const float* __restrict__ w,
    float* __restrict__ out, int applySelu) {
  __shared__ float sred[8];
  const int n = blockIdx.x, t = threadIdx.x;
  const long base = (long)n * 1024 + t * 4;
  float4 v = *(const float4*)&in[base];
  float s = v.x + v.y + v.z + v.w;
  s = wave_reduce_sum(s);
  const int wid = t >> 6;
  if ((t & 63) == 0) sred[wid] = s;
  __syncthreads();
  const float mu = (sred[0] + sred[1] + sred[2] + sred[3]) * (1.f / 1024.f);
  float4 d;
  d.x = v.x - mu; d.y = v.y - mu; d.z = v.z - mu; d.w = v.w - mu;
  float sq = d.x * d.x + d.y * d.y + d.z * d.z + d.w * d.w;
  sq = wave_reduce_sum(sq);
  if ((t & 63) == 0) sred[4 + wid] = sq;
  __syncthreads();
  const float var = (sred[4] + sred[5] + sred[6] + sred[7]) * (1.f / 1024.f);
  const float rstd = rsqrtf(var + 1e-5f);
  const float4 w4 = *(const float4*)&w[t * 4];
  float4 o4;
  o4.x = d.x * rstd * w4.x; o4.y = d.y * rstd * w4.y;
  o4.z = d.z * rstd * w4.z; o4.w = d.w * rstd * w4.w;
  if (applySelu) {
    o4.x = selu_f(o4.x); o4.y = selu_f(o4.y); o4.z = selu_f(o4.z); o4.w = selu_f(o4.w);
  }
  *(float4*)&out[base] = o4;
}

// ---------------------------------------------------------------------------
// Tiled SGEMM: C[m,n] = sum_k A[m,k]*B[k,n] (+ Res). 128x128x8 tile, 256 thr,
// 8x8 micro-tile. WT=false: W is (K,N) row-major. WT=true: W is (N,K).
// blockIdx.z batches heads via aZ/wZ/cZ element offsets.
// ---------------------------------------------------------------------------
template <bool WT>
__global__ __launch_bounds__(256) void gemm_kernel(
    const float* __restrict__ A, int lda, long aZ,
    const float* __restrict__ W, int ldw, long wZ,
    const float* __restrict__ Res, int ldr, long rZ,
    float* __restrict__ C, int ldc, long cZ,
    int M, int N, int Kd) {
  __shared__ float As[8][128];
  __shared__ float Bs[8][132];
  const int bn = blockIdx.x * 128;
  const int bm = blockIdx.y * 128;
  A += (long)blockIdx.z * aZ;
  W += (long)blockIdx.z * wZ;
  C += (long)blockIdx.z * cZ;
  const float* Rp = Res ? Res + (long)blockIdx.z * rZ : nullptr;
  const int t = threadIdx.x;
  const int tx = t & 15, ty = t >> 4;

  float acc[8][8] = {};

  const int ar = t >> 1, ak = (t & 1) * 4;
  for (int k0 = 0; k0 < Kd; k0 += 8) {
    const float4 av = *(const float4*)&A[(long)(bm + ar) * lda + k0 + ak];
    float4 bv;
    int bk, bn4, bnr, bk4;
    if (!WT) {
      bk = t >> 5; bn4 = (t & 31) << 2;
      bv = *(const float4*)&W[(long)(k0 + bk) * ldw + bn + bn4];
    } else {
      bnr = t >> 1; bk4 = (t & 1) * 4;
      bv = *(const float4*)&W[(long)(bn + bnr) * ldw + k0 + bk4];
    }
    As[ak + 0][ar] = av.x; As[ak + 1][ar] = av.y;
    As[ak + 2][ar] = av.z; As[ak + 3][ar] = av.w;
    if (!WT) {
      *(float4*)&Bs[bk][bn4] = bv;
    } else {
      Bs[bk4 + 0][bnr] = bv.x; Bs[bk4 + 1][bnr] = bv.y;
      Bs[bk4 + 2][bnr] = bv.z; Bs[bk4 + 3][bnr] = bv.w;
    }
    __syncthreads();
#pragma unroll
    for (int kk = 0; kk < 8; ++kk) {
      float a0[8], b0[8];
      *(float4*)&a0[0] = *(const float4*)&As[kk][ty * 8];
      *(float4*)&a0[4] = *(const float4*)&As[kk][ty * 8 + 4];
      *(float4*)&b0[0] = *(const float4*)&Bs[kk][tx * 8];
      *(float4*)&b0[4] = *(const float4*)&Bs[kk][tx * 8 + 4];
#pragma unroll
      for (int i = 0; i < 8; ++i)
#pragma unroll
        for (int j = 0; j < 8; ++j) acc[i][j] += a0[i] * b0[j];
    }
    __syncthreads();
  }

  const int row0 = bm + ty * 8, col0 = bn + tx * 8;
#pragma unroll
  for (int i = 0; i < 8; ++i) {
#pragma unroll
    for (int jq = 0; jq < 8; jq += 4) {
      float4 o;
      o.x = acc[i][jq + 0]; o.y = acc[i][jq + 1];
      o.z = acc[i][jq + 2]; o.w = acc[i][jq + 3];
      if (Rp) {
        const float4 r4 = *(const float4*)&Rp[(long)(row0 + i) * ldr + col0 + jq];
        o.x += r4.x; o.y += r4.y; o.z += r4.z; o.w += r4.w;
      }
      *(float4*)&C[(long)(row0 + i) * ldc + col0 + jq] = o;
    }
  }
}

// ---------------------------------------------------------------------------
// Depthwise causal conv1d (K=4) + SiLU. One float4 channel-group per thread.
// ---------------------------------------------------------------------------
__global__ __launch_bounds__(256) void conv_silu_kernel(
    const float* __restrict__ in, int ld_in,
    const float* __restrict__ w, const float* __restrict__ bias,
    float* __restrict__ out, int ld_out, int C) {
  const int idx = blockIdx.x * 256 + threadIdx.x;
  const int gpr = C >> 2;
  const int n = idx / gpr;
  const int c = (idx - n * gpr) << 2;
  const int s = n & 1023;
  float4 acc = *(const float4*)&bias[c];
  const float* wc = &w[c * 4];
#pragma unroll
  for (int tap = 0; tap < 4; ++tap) {
    const int sp = s - 3 + tap;
    if (sp >= 0) {
      const float4 xv = *(const float4*)&in[(long)(n - 3 + tap) * ld_in + c];
      acc.x += xv.x * wc[0 + tap];
      acc.y += xv.y * wc[4 + tap];
      acc.z += xv.z * wc[8 + tap];
      acc.w += xv.w * wc[12 + tap];
    }
  }
  acc.x = silu_f(acc.x); acc.y = silu_f(acc.y);
  acc.z = silu_f(acc.z); acc.w = silu_f(acc.w);
  *(float4*)&out[(long)n * ld_out + c] = acc;
}

// ---------------------------------------------------------------------------
// Fold the 4x4 block-diagonal q/k/v maps into Wig/Wfg.
// ---------------------------------------------------------------------------
__global__ __launch_bounds__(256) void wtilde_kernel(
    const float* __restrict__ Wq, const float* __restrict__ Wk,
    const float* __restrict__ Wv, const float* __restrict__ Wig,
    const float* __restrict__ Wfg,
    float* __restrict__ wqk_ig, float* __restrict__ wv_ig,
    float* __restrict__ wqk_fg, float* __restrict__ wv_fg) {
  const int idx = blockIdx.x * 256 + threadIdx.x;  // 8192
  const int c = idx >> 2, hm = idx & 3;
  const int bk = c >> 2, i = c & 3;
  float sqk_i = 0, sv_i = 0, sqk_f = 0, sv_f = 0;
#pragma unroll
  for (int o = 0; o < 4; ++o) {
    const float wq = Wq[(bk * 4 + o) * 4 + i];
    const float wk = Wk[(bk * 4 + o) * 4 + i];
    const float wv = Wv[(bk * 4 + o) * 4 + i];
    const int rq = bk * 4 + o;
    sqk_i += wq * Wig[rq * 4 + hm] + wk * Wig[(2048 + rq) * 4 + hm];
    sv_i  += wv * Wig[(4096 + rq) * 4 + hm];
    sqk_f += wq * Wfg[rq * 4 + hm] + wk * Wfg[(2048 + rq) * 4 + hm];
    sv_f  += wv * Wfg[(4096 + rq) * 4 + hm];
  }
  wqk_ig[idx] = sqk_i; wv_ig[idx] = sv_i;
  wqk_fg[idx] = sqk_f; wv_fg[idx] = sv_f;
}

// ---------------------------------------------------------------------------
// ig/fg: per token, 8 dot products of length 4096 (xc part + xi part).
// ---------------------------------------------------------------------------
__global__ __launch_bounds__(256) void igfg_kernel(
    const float* __restrict__ xc, const float* __restrict__ up,
    const float* __restrict__ wqk_ig, const float* __restrict__ wv_ig,
    const float* __restrict__ wqk_fg, const float* __restrict__ wv_fg,
    const float* __restrict__ big, const float* __restrict__ bfg,
    float* __restrict__ ig, float* __restrict__ fg) {
  __shared__ float red[4][8];
  const int n = blockIdx.x, t = threadIdx.x;
  float ai[4] = {0, 0, 0, 0}, af[4] = {0, 0, 0, 0};
  for (int c = t; c < 2048; c += 256) {
    const float xcv = xc[(long)n * 2048 + c];
    const float xiv = up[(long)n * 4096 + c];
    const float4 wiq = *(const float4*)&wqk_ig[c * 4];
    const float4 wiv = *(const float4*)&wv_ig[c * 4];
    const float4 wfq = *(const float4*)&wqk_fg[c * 4];
    const float4 wfv = *(const float4*)&wv_fg[c * 4];
    ai[0] += xcv * wiq.x + xiv * wiv.x;
    ai[1] += xcv * wiq.y + xiv * wiv.y;
    ai[2] += xcv * wiq.z + xiv * wiv.z;
    ai[3] += xcv * wiq.w + xiv * wiv.w;
    af[0] += xcv * wfq.x + xiv * wfv.x;
    af[1] += xcv * wfq.y + xiv * wfv.y;
    af[2] += xcv * wfq.z + xiv * wfv.z;
    af[3] += xcv * wfq.w + xiv * wfv.w;
  }
#pragma unroll
  for (int j = 0; j < 4; ++j) {
    ai[j] = wave_reduce_sum(ai[j]);
    af[j] = wave_reduce_sum(af[j]);
  }
  const int wid = t >> 6;
  if ((t & 63) == 0) {
#pragma unroll
    for (int j = 0; j < 4; ++j) { red[wid][j] = ai[j]; red[wid][4 + j] = af[j]; }
  }
  __syncthreads();
  if (t < 8) {
    const float v = red[0][t] + red[1][t] + red[2][t] + red[3][t];
    const int b = n >> 10, s = n & 1023;
    if (t < 4) ig[((long)b * 4 + t) * 1024 + s] = v + big[t];
    else       fg[((long)b * 4 + (t - 4)) * 1024 + s] = v + bfg[t - 4];
  }
}

// ---------------------------------------------------------------------------
// lfc = cumsum(log_sigmoid(fg)) over S per (b,h). Hillis-Steele in LDS.
// ---------------------------------------------------------------------------
__global__ __launch_bounds__(1024) void lfc_kernel(
    const float* __restrict__ fg, float* __restrict__ lfc) {
  __shared__ float sh[1024];
  const int bh = blockIdx.x, t = threadIdx.x;
  const float x = fg[(long)bh * 1024 + t];
  sh[t] = fminf(x, 0.f) - log1pf(expf(-fabsf(x)));
  __syncthreads();
  for (int off = 1; off < 1024; off <<= 1) {
    const float add = (t >= off) ? sh[t - off] : 0.f;
    __syncthreads();
    sh[t] += add;
    __syncthreads();
  }
  lfc[(long)bh * 1024 + t] = sh[t];
}

// ---------------------------------------------------------------------------
// v = headwise(xi, Wv) in place over the xi region of `up`.
// ---------------------------------------------------------------------------
__global__ __launch_bounds__(256) void hv_inplace_kernel(
    float* __restrict__ up, const float* __restrict__ Wv) {
  const int idx = blockIdx.x * 256 + threadIdx.x;  // Ntok*512
  const int n = idx >> 9, bk = idx & 511;
  const long a = (long)n * 4096 + (bk << 2);
  const float4 xv = *(const float4*)&up[a];
  const float* wb = &Wv[bk << 4];
  float4 o;
  o.x = xv.x * wb[0]  + xv.y * wb[1]  + xv.z * wb[2]  + xv.w * wb[3];
  o.y = xv.x * wb[4]  + xv.y * wb[5]  + xv.z * wb[6]  + xv.w * wb[7];
  o.z = xv.x * wb[8]  + xv.y * wb[9]  + xv.z * wb[10] + xv.w * wb[11];
  o.w = xv.x * wb[12] + xv.y * wb[13] + xv.z * wb[14] + xv.w * wb[15];
  *(float4*)&up[a] = o;
}

// ---------------------------------------------------------------------------
// mLSTM parallel, flash-style. Grid (32 rowblocks, 16 bh), 256 threads.
// ---------------------------------------------------------------------------
__global__ __launch_bounds__(256) void mlstm_attn_kernel(
    const float* __restrict__ xc, const float* __restrict__ up,
    const float* __restrict__ Wq, const float* __restrict__ Wk,
    const float* __restrict__ lfc, const float* __restrict__ igv,
    float* __restrict__ hout) {
  __shared__ float q_s[32][516];
  __shared__ float kv_s[32][516];
  __shared__ float p_s[32][36];
  __shared__ float lfci_s[32], lfcj_s[32], igj_s[32];
  const int t = threadIdx.x;
  const int ti = t >> 5, tj = t & 31;
  const int i0 = blockIdx.x * 32;
  const int bh = blockIdx.y;
  const int b = bh >> 2, h = bh & 3;
  const float kscale = 0.04419417382415922f;  // 512^-0.5

  for (int idx = t; idx < 32 * 128; idx += 256) {
    const int r = idx >> 7, g = idx & 127;
    const float4 xv =
        *(const float4*)&xc[((long)(b * 1024 + i0 + r)) * 2048 + h * 512 + (g << 2)];
    const float* wb = Wq + ((h * 128 + g) << 4);
    float4 q4;
    q4.x = xv.x * wb[0]  + xv.y * wb[1]  + xv.z * wb[2]  + xv.w * wb[3];
    q4.y = xv.x * wb[4]  + xv.y * wb[5]  + xv.z * wb[6]  + xv.w * wb[7];
    q4.z = xv.x * wb[8]  + xv.y * wb[9]  + xv.z * wb[10] + xv.w * wb[11];
    q4.w = xv.x * wb[12] + xv.y * wb[13] + xv.z * wb[14] + xv.w * wb[15];
    *(float4*)&q_s[r][g << 2] = q4;
  }
  if (t < 32) lfci_s[t] = lfc[(long)bh * 1024 + i0 + t];

  const int r0 = ti * 4;
  float m_run[4], ssum[4], accv[4][16];
#pragma unroll
  for (int e = 0; e < 4; ++e) {
    m_run[e] = -INFINITY; ssum[e] = 0.f;
#pragma unroll
    for (int u = 0; u < 16; ++u) accv[e][u] = 0.f;
  }

  for (int j0 = 0; j0 <= i0; j0 += 32) {
    __syncthreads();
    for (int idx = t; idx < 32 * 128; idx += 256) {
      const int r = idx >> 7, g = idx & 127;
      const float4 xv =
          *(const float4*)&xc[((long)(b * 1024 + j0 + r)) * 2048 + h * 512 + (g << 2)];
      const float* wb = Wk + ((h * 128 + g) << 4);
      float4 k4;
      k4.x = (xv.x * wb[0]  + xv.y * wb[1]  + xv.z * wb[2]  + xv.w * wb[3])  * kscale;
      k4.y = (xv.x * wb[4]  + xv.y * wb[5]  + xv.z * wb[6]  + xv.w * wb[7])  * kscale;
      k4.z = (xv.x * wb[8]  + xv.y * wb[9]  + xv.z * wb[10] + xv.w * wb[11]) * kscale;
      k4.w = (xv.x * wb[12] + xv.y * wb[13] + xv.z * wb[14] + xv.w * wb[15]) * kscale;
      *(float4*)&kv_s[r][g << 2] = k4;
    }
    if (t < 32) {
      lfcj_s[t] = lfc[(long)bh * 1024 + j0 + t];
      igj_s[t] = igv[(long)bh * 1024 + j0 + t];
    }
    __syncthreads();

    float sv[4] = {0.f, 0.f, 0.f, 0.f};
#pragma unroll 2
    for (int d = 0; d < 512; d += 4) {
      const float4 kv = *(const float4*)&kv_s[tj][d];
#pragma unroll
      for (int e = 0; e < 4; ++e) {
        const float4 qv = *(const float4*)&q_s[r0 + e][d];
        sv[e] += qv.x * kv.x + qv.y * kv.y + qv.z * kv.z + qv.w * kv.w;
      }
    }
    const float lfcj = lfcj_s[tj], igj = igj_s[tj];
    float mt[4], logd[4];
    bool valid[4];
#pragma unroll
    for (int e = 0; e < 4; ++e) {
      valid[e] = (j0 + tj) <= (i0 + r0 + e);
      logd[e] = lfci_s[r0 + e] - lfcj + igj;
      mt[e] = valid[e] ? logd[e] : -INFINITY;
    }
#pragma unroll
    for (int o = 16; o > 0; o >>= 1) {
#pragma unroll
      for (int e = 0; e < 4; ++e) mt[e] = fmaxf(mt[e], __shfl_xor(mt[e], o));
    }
    float p[4];
#pragma unroll
    for (int e = 0; e < 4; ++e) {
      const float mn = fmaxf(m_run[e], mt[e]);
      const float scale = __expf(m_run[e] - mn);
      m_run[e] = mn;
      p[e] = valid[e] ? sv[e] * __expf(logd[e] - mn) : 0.f;
      float ps = p[e];
#pragma unroll
      for (int o = 16; o > 0; o >>= 1) ps += __shfl_xor(ps, o);
      ssum[e] = ssum[e] * scale + ps;
#pragma unroll
      for (int u = 0; u < 16; ++u) accv[e][u] *= scale;
      p_s[r0 + e][tj] = p[e];
    }
    __syncthreads();

    for (int idx = t; idx < 32 * 128; idx += 256) {
      const int r = idx >> 7, g = idx & 127;
      const float4 vv =
          *(const float4*)&up[((long)(b * 1024 + j0 + r)) * 4096 + h * 512 + (g << 2)];
      *(float4*)&kv_s[r][g << 2] = vv;
    }
    __syncthreads();

#pragma unroll 2
    for (int j = 0; j < 32; ++j) {
      const float pj0 = p_s[r0 + 0][j];
      const float pj1 = p_s[r0 + 1][j];
      const float pj2 = p_s[r0 + 2][j];
      const float pj3 = p_s[r0 + 3][j];
#pragma unroll
      for (int u = 0; u < 16; ++u) {
        const float vv = kv_s[j][tj + (u << 5)];
        accv[0][u] += pj0 * vv;
        accv[1][u] += pj1 * vv;
        accv[2][u] += pj2 * vv;
        accv[3][u] += pj3 * vv;
      }
    }
  }

#pragma unroll
  for (int e = 0; e < 4; ++e) {
    const float norm = fmaxf(fabsf(ssum[e]), __expf(-m_run[e]));
    const float inv = 1.f / (norm + 1e-6f);
    const long rowbase = ((long)(b * 1024 + i0 + r0 + e)) * 2048 + h * 512;
#pragma unroll
    for (int u = 0; u < 16; ++u) hout[rowbase + tj + (u << 5)] = accv[e][u] * inv;
  }
}

// ---------------------------------------------------------------------------
// Block-0 epilogue: per-head LN of h (DH=512), then (hn + skip*xc)*silu(z).
// ---------------------------------------------------------------------------
__global__ __launch_bounds__(128) void mhgate_kernel(
    float* __restrict__ hbuf, const float* __restrict__ mhw,
    const float* __restrict__ skip, const float* __restrict__ xc,
    const float* __restrict__ up) {
  __shared__ float sred[4];
  const int nh = blockIdx.x, t = threadIdx.x;
  const int n = nh >> 2, hd = nh & 3;
  const long base = (long)n * 2048 + hd * 512 + t * 4;
  const float4 v = *(const float4*)&hbuf[base];
  float s = wave_reduce_sum(v.x + v.y + v.z + v.w);
  if ((t & 63) == 0) sred[t >> 6] = s;
  __syncthreads();
  const float mu = (sred[0] + sred[1]) * (1.f / 512.f);
  float4 d;
  d.x = v.x - mu; d.y = v.y - mu; d.z = v.z - mu; d.w = v.w - mu;
  float sq = wave_reduce_sum(d.x * d.x + d.y * d.y + d.z * d.z + d.w * d.w);
  if ((t & 63) == 0) sred[2 + (t >> 6)] = sq;
  __syncthreads();
  const float rstd = rsqrtf((sred[2] + sred[3]) * (1.f / 512.f) + 1e-5f);
  const int ch = hd * 512 + t * 4;
  const float4 w4 = *(const float4*)&mhw[ch];
  const float4 sk4 = *(const float4*)&skip[ch];
  const float4 xc4 = *(const float4*)&xc[(long)n * 2048 + ch];
  const float4 z4 = *(const float4*)&up[(long)n * 4096 + 2048 + ch];
  float4 o;
  o.x = (d.x * rstd * w4.x + sk4.x * xc4.x) * silu_f(z4.x);
  o.y = (d.y * rstd * w4.y + sk4.y * xc4.y) * silu_f(z4.y);
  o.z = (d.z * rstd * w4.z + sk4.z * xc4.z) * silu_f(z4.z);
  o.w = (d.w * rstd * w4.w + sk4.w * xc4.w) * silu_f(z4.w);
  *(float4*)&hbuf[base] = o;
}

// ---------------------------------------------------------------------------
// sLSTM scan, 64 blocks: blockIdx.x = g*16 + bh (g = gate, bh = (b,h)).
// Each thread holds a 64-row slice of one R column in registers (64 VGPR).
// Per step: LDS-broadcast matvec -> preact exchange via global `ex`
// (parity double-buffered, 16384 floats each) + per-(bh,step) atomic counter
// flag -> all 4 gate-blocks redundantly update state (c,n,m,h).
// Parity reuse is safe: a block writes step s+2's buffer only after
// observing all flags for s+1, which requires every block to have finished
// reading step s. 64 blocks x 16 waves <= 2 blocks/CU on 256 CUs and
// <=128 VGPR via launch_bounds -> all co-resident.
// Spin is bounded: a protocol bug degrades to a wrong-result fail, not a
// harness-killing hang.
// ---------------------------------------------------------------------------
__global__ __launch_bounds__(1024, 4) void slstm_scan64_kernel(
    const float* __restrict__ gi, const float* __restrict__ gf,
    const float* __restrict__ gz, const float* __restrict__ go,
    const float* __restrict__ R, const float* __restrict__ bias,
    float* __restrict__ ex, int* __restrict__ flags,
    float* __restrict__ hsout) {
  __shared__ float h_cur[256];
  __shared__ float psum[1024];
  const int t = threadIdx.x;
  const int g = blockIdx.x >> 4;
  const int bh = blockIdx.x & 15;
  const int b = bh >> 2, hd = bh & 3;
  const int c = t & 255, ks = t >> 8;

  const float* gx = (g == 0) ? gi : (g == 1) ? gf : (g == 2) ? gz : go;

  // register-resident R slice: r[j] = R[hd][ks*64+j][g*256+c]
  float r[64];
  {
    const float* Rp = R + ((long)(hd * 256 + ks * 64)) * 1024 + g * 256 + c;
#pragma unroll
    for (int j = 0; j < 64; ++j) r[j] = Rp[(long)j * 1024];
  }

  float bown = 0.f, cc = 0.f, nn = 0.f, m = 0.f, gx_val = 0.f;
  if (t < 256) {
    h_cur[t] = 0.f;
    bown = bias[(hd * 4 + g) * 256 + c];
    gx_val = gx[((long)(b * 1024)) * 1024 + hd * 256 + c];  // s = 0
  }
  int* flg = flags + bh;
  __syncthreads();

  for (int s = 0; s < 1024; ++s) {
    // 1) matvec partial: out[c] partial over rows [ks*64, ks*64+64)
    float acc = 0.f;
    const float* hv = &h_cur[ks << 6];
#pragma unroll
    for (int j = 0; j < 64; j += 4) {
      const float4 h4 = *(const float4*)&hv[j];
      acc += h4.x * r[j] + h4.y * r[j + 1] + h4.z * r[j + 2] + h4.w * r[j + 3];
    }
    psum[t] = acc;
    __syncthreads();

    // 2) preact (x + ry + bias) -> exchange buffer (parity double-buffer,
    //    16384 floats per parity: bh*1024 + g*256 + c)
    float* exs = ex + ((s & 1) << 14);
    if (t < 256) {
      const float pre = psum[c] + psum[256 + c] + psum[512 + c] + psum[768 + c]
                        + gx_val + bown;
      exs[(bh * 4 + g) * 256 + c] = pre;
    }
    __threadfence();  // drain ex stores to the coherent point
    // prefetch next step's gate-x preact (overlaps the spin)
    if (t < 256 && s < 1023) {
      gx_val = gx[((long)(b * 1024 + s + 1)) * 1024 + hd * 256 + c];
    }
    if (t == 0) {
      __hip_atomic_fetch_add(&flg[s * 16], 1, __ATOMIC_RELEASE,
                             __HIP_MEMORY_SCOPE_AGENT);
      int it = 0;
      while (__hip_atomic_load(&flg[s * 16], __ATOMIC_ACQUIRE,
                               __HIP_MEMORY_SCOPE_AGENT) < 4 &&
             it < 100000) {
        __builtin_amdgcn_s_sleep(1);
        ++it;
      }
    }
    __syncthreads();

    // 3) state update (replicated in all 4 gate-blocks)
    if (t < 256) {
      const float* exb = exs + bh * 4 * 256;
      const float ir = __hip_atomic_load(&exb[c], __ATOMIC_RELAXED,
                                         __HIP_MEMORY_SCOPE_AGENT);
      const float fr = __hip_atomic_load(&exb[256 + c], __ATOMIC_RELAXED,
                                         __HIP_MEMORY_SCOPE_AGENT);
      const float zr = __hip_atomic_load(&exb[512 + c], __ATOMIC_RELAXED,
                                         __HIP_MEMORY_SCOPE_AGENT);
      const float og = __hip_atomic_load(&exb[768 + c], __ATOMIC_RELAXED,
                                         __HIP_MEMORY_SCOPE_AGENT);
      const float lsf = fminf(fr, 0.f) - log1pf(expf(-fabsf(fr)));
      const float lfm = m + lsf;
      const float mn = fmaxf(ir, lfm);
      const float igate = expf(ir - mn);
      const float fgate = expf(lfm - mn);
      cc = fgate * cc + igate * tanhf(zr);
      nn = fgate * nn + igate;
      const float hnew = (1.f / (1.f + expf(-og))) * (cc / (nn + 1e-6f));
      m = mn;
      h_cur[c] = hnew;
      if (g == 0) hsout[((long)(b * 1024 + s)) * 1024 + hd * 256 + c] = hnew;
    }
    __syncthreads();
  }
}

// ---------------------------------------------------------------------------
// sLSTM epilogue: x2 = x1 + mh_layernorm(hs) * w.
// ---------------------------------------------------------------------------
__global__ __launch_bounds__(64) void mhres_kernel(
    const float* __restrict__ hs, const float* __restrict__ w,
    const float* __restrict__ x1, float* __restrict__ x2) {
  const int nh = blockIdx.x, t = threadIdx.x;
  const int n = nh >> 2, hd = nh & 3;
  const long base = (long)n * 1024 + hd * 256 + t * 4;
  const float4 v = *(const float4*)&hs[base];
  const float mu = wave_reduce_sum(v.x + v.y + v.z + v.w) * (1.f / 256.f);
  float4 d;
  d.x = v.x - mu; d.y = v.y - mu; d.z = v.z - mu; d.w = v.w - mu;
  const float var =
      wave_reduce_sum(d.x * d.x + d.y * d.y + d.z * d.z + d.w * d.w) * (1.f / 256.f);
  const float rstd = rsqrtf(var + 1e-5f);
  const float4 w4 = *(const float4*)&w[hd * 256 + t * 4];
  const float4 r4 = *(const float4*)&x1[base];
  float4 o;
  o.x = r4.x + d.x * rstd * w4.x;
  o.y = r4.y + d.y * rstd * w4.y;
  o.z = r4.z + d.z * rstd * w4.z;
  o.w = r4.w + d.w * rstd * w4.w;
  *(float4*)&x2[base] = o;
}

// ---------------------------------------------------------------------------
// GeGLU (tanh-approx gelu), in place over g.
// ---------------------------------------------------------------------------
__global__ __launch_bounds__(256) void geglu_kernel(float* __restrict__ ffn) {
  const int idx = blockIdx.x * 256 + threadIdx.x;
  const int n = idx / 1344, j = idx % 1344;
  const long base = (long)n * 2688;
  const float g = ffn[base + j];
  const float u = ffn[base + 1344 + j];
  const float t3 = 0.7978845608028654f * (g + 0.044715f * g * g * g);
  ffn[base + j] = 0.5f * g * (1.f + tanhf(t3)) * u;
}

// ---------------------------------------------------------------------------
// Column mean over S.
// ---------------------------------------------------------------------------
__global__ __launch_bounds__(256) void colmean_kernel(
    const float* __restrict__ tmp, float* __restrict__ feat) {
  const int b = blockIdx.x >> 2;
  const int ch = ((blockIdx.x & 3) << 8) + threadIdx.x;
  const float* p = tmp + (long)b * 1024 * 1024 + ch;
  float s = 0.f;
#pragma unroll 4
  for (int si = 0; si < 1024; ++si) s += p[(long)si * 1024];
  feat[b * 1024 + ch] = s * (1.f / 1024.f);
}

// ---------------------------------------------------------------------------
// Classification heads.
// ---------------------------------------------------------------------------
__global__ __launch_bounds__(256) void head_kernel(
    const float* __restrict__ feat, const float* __restrict__ We,
    const float* __restrict__ be, const float* __restrict__ Ws,
    const float* __restrict__ bs, float* __restrict__ out) {
  __shared__ float sred[4];
  const int o = blockIdx.x, t = threadIdx.x;
  const int b = o / 10, j = o % 10;
  const float* wcol;
  int ld;
  float bias;
  if (j < 7) { wcol = We + j; ld = 7; bias = be[j]; }
  else       { wcol = Ws + (j - 7); ld = 3; bias = bs[j - 7]; }
  float s = 0.f;
  for (int d = t; d < 1024; d += 256) s += feat[b * 1024 + d] * wcol[d * ld];
  s = wave_reduce_sum(s);
  if ((t & 63) == 0) sred[t >> 6] = s;
  __syncthreads();
  if (t == 0) out[o] = sred[0] + sred[1] + sred[2] + sred[3] + bias;
}

// ===========================================================================
extern "C" void kernel_launch(void* const* d_in, const int* in_sizes, int n_in,
                              void* d_out, int out_size, void* d_ws, size_t ws_size,
                              hipStream_t stream) {
  (void)in_sizes; (void)n_in; (void)out_size; (void)ws_size;
  const float* x        = (const float*)d_in[0];
  const float* m_ln_w   = (const float*)d_in[1];
  const float* m_Wup    = (const float*)d_in[2];
  const float* m_conv_w = (const float*)d_in[3];
  const float* m_conv_b = (const float*)d_in[4];
  const float* m_Wq     = (const float*)d_in[5];
  const float* m_Wk     = (const float*)d_in[6];
  const float* m_Wv     = (const float*)d_in[7];
  const float* m_Wig    = (const float*)d_in[8];
  const float* m_big    = (const float*)d_in[9];
  const float* m_Wfg    = (const float*)d_in[10];
  const float* m_bfg    = (const float*)d_in[11];
  const float* m_mhln_w = (const float*)d_in[12];
  const float* m_skip   = (const float*)d_in[13];
  const float* m_Wdown  = (const float*)d_in[14];
  const float* s_ln_w   = (const float*)d_in[15];
  const float* s_conv_w = (const float*)d_in[16];
  const float* s_conv_b = (const float*)d_in[17];
  const float* s_Wi     = (const float*)d_in[18];
  const float* s_Wf     = (const float*)d_in[19];
  const float* s_Wz     = (const float*)d_in[20];
  const float* s_Wo     = (const float*)d_in[21];
  const float* s_R      = (const float*)d_in[22];
  const float* s_b      = (const float*)d_in[23];
  const float* s_mhln_w = (const float*)d_in[24];
  const float* s_ffn_ln_w = (const float*)d_in[25];
  const float* s_Wup    = (const float*)d_in[26];
  const float* s_Wdown2 = (const float*)d_in[27];
  const float* post_ln_w = (const float*)d_in[28];
  const float* h_We     = (const float*)d_in[29];
  const float* h_be     = (const float*)d_in[30];
  const float* h_Ws     = (const float*)d_in[31];
  const float* h_bs     = (const float*)d_in[32];
  float* out = (float*)d_out;
  float* ws = (float*)d_ws;

  float* xn = ws + OFF_XN;
  float* up = ws + OFF_UP;
  float* xc = ws + OFF_XC;
  float* hsbuf = ws + OFF_HS;
  float* hb = ws + OFF_H;
  float* x1 = ws + OFF_X1;
  float* wqk_ig = ws + OFF_SM;
  float* wv_ig  = wqk_ig + 8192;
  float* wqk_fg = wqk_ig + 16384;
  float* wv_fg  = wqk_ig + 24576;
  float* igb    = ws + OFF_SM + 32768;
  float* fgb    = igb + 16384;
  float* lfcb   = igb + 32768;
  float* feat   = igb + 49152;
  float* exbuf  = ws + OFF_SM + 98304;                  // 2*16384 floats
  int*   flags  = (int*)(ws + OFF_SM + 98304 + 32768);  // 16384 ints

  // ---- block 0: mLSTM ----
  ln1024_kernel<<<4096, 256, 0, stream>>>(x, m_ln_w, xn, 0);
  gemm_kernel<false><<<dim3(32, 32, 1), 256, 0, stream>>>(
      xn, 1024, 0, m_Wup, 4096, 0, nullptr, 0, 0, up, 4096, 0, 4096, 4096, 1024);
  conv_silu_kernel<<<(4096 * 512) / 256, 256, 0, stream>>>(
      up, 4096, m_conv_w, m_conv_b, xc, 2048, 2048);
  wtilde_kernel<<<32, 256, 0, stream>>>(m_Wq, m_Wk, m_Wv, m_Wig, m_Wfg,
                                        wqk_ig, wv_ig, wqk_fg, wv_fg);
  igfg_kernel<<<4096, 256, 0, stream>>>(xc, up, wqk_ig, wv_ig, wqk_fg, wv_fg,
                                        m_big, m_bfg, igb, fgb);
  lfc_kernel<<<16, 1024, 0, stream>>>(fgb, lfcb);
  hv_inplace_kernel<<<8192, 256, 0, stream>>>(up, m_Wv);
  mlstm_attn_kernel<<<dim3(32, 16), 256, 0, stream>>>(
      xc, up, m_Wq, m_Wk, lfcb, igb, hb);
  mhgate_kernel<<<16384, 128, 0, stream>>>(hb, m_mhln_w, m_skip, xc, up);
  gemm_kernel<false><<<dim3(8, 32, 1), 256, 0, stream>>>(
      hb, 2048, 0, m_Wdown, 1024, 0, x, 1024, 0, x1, 1024, 0, 4096, 1024, 2048);

  // ---- block 1: sLSTM ----
  ln1024_kernel<<<4096, 256, 0, stream>>>(x1, s_ln_w, xn, 0);
  conv_silu_kernel<<<(4096 * 256) / 256, 256, 0, stream>>>(
      xn, 1024, s_conv_w, s_conv_b, xc, 1024, 1024);
  float* gi = up;
  float* gf = up + (4l << 20);
  float* gz = up + (8l << 20);
  float* go = up + (12l << 20);
  gemm_kernel<true><<<dim3(2, 32, 4), 256, 0, stream>>>(
      xc, 1024, 256, s_Wi, 256, 65536, nullptr, 0, 0, gi, 1024, 256, 4096, 256, 256);
  gemm_kernel<true><<<dim3(2, 32, 4), 256, 0, stream>>>(
      xc, 1024, 256, s_Wf, 256, 65536, nullptr, 0, 0, gf, 1024, 256, 4096, 256, 256);
  gemm_kernel<true><<<dim3(2, 32, 4), 256, 0, stream>>>(
      xn, 1024, 256, s_Wz, 256, 65536, nullptr, 0, 0, gz, 1024, 256, 4096, 256, 256);
  gemm_kernel<true><<<dim3(2, 32, 4), 256, 0, stream>>>(
      xn, 1024, 256, s_Wo, 256, 65536, nullptr, 0, 0, go, 1024, 256, 4096, 256, 256);
  hipMemsetAsync(flags, 0, 16384 * sizeof(int), stream);
  slstm_scan64_kernel<<<64, 1024, 0, stream>>>(gi, gf, gz, go, s_R, s_b,
                                               exbuf, flags, hsbuf);
  mhres_kernel<<<16384, 64, 0, stream>>>(hsbuf, s_mhln_w, x1, hb);
  float* x2 = hb;

  // ---- FFN ----
  ln1024_kernel<<<4096, 256, 0, stream>>>(x2, s_ffn_ln_w, xn, 0);
  float* ffn = up;
  gemm_kernel<false><<<dim3(21, 32, 1), 256, 0, stream>>>(
      xn, 1024, 0, s_Wup, 2688, 0, nullptr, 0, 0, ffn, 2688, 0, 4096, 2688, 1024);
  geglu_kernel<<<(4096 * 1344) / 256, 256, 0, stream>>>(ffn);
  gemm_kernel<false><<<dim3(8, 32, 1), 256, 0, stream>>>(
      ffn, 2688, 0, s_Wdown2, 1024, 0, x2, 1024, 0, x1, 1024, 0, 4096, 1024, 1344);
  float* x3 = x1;

  // ---- post: LN + SELU + mean pool + heads ----
  ln1024_kernel<<<4096, 256, 0, stream>>>(x3, post_ln_w, xn, 1);
  colmean_kernel<<<16, 256, 0, stream>>>(xn, feat);
  head_kernel<<<40, 256, 0, stream>>>(feat, h_We, h_be, h_Ws, h_bs, out);
}

// Round 5
// 12058.356 us; speedup vs baseline: 1.7009x; 1.7009x over previous
//
#include <hip/hip_runtime.h>
#include <hip/hip_bf16.h>

// ============================================================================
// xLSTM audio model, fp32 (+ bf16-packed sLSTM recurrent matrix).
// B=4, S=1024, D=1024, INNER=2048, NH_M=4, DH_M=512, NH_S=4, DH_S=256,
// K(conv)=4, FF_UP=1344. N = B*S = 4096 tokens.
//
// R5: revert R4's 64-block exchange scan (cross-XCD agent-scope sync measured
// ~17 us/step, 84 MB HBM writeback -> 2-5x SLOWER). Back to 16-block
// single-block-per-(b,h) scan (R1: 8.8 us/step, per-CU L2->L1 load-BW bound
// streaming 1 MB fp32 R/step). This round halves the streamed bytes:
// R packed to bf16, 4 rows per uint2, unpacked with shift/mask in VALU.
// ============================================================================

#define DEV_INLINE __device__ __forceinline__

constexpr long OFF_XN = 0;
constexpr long OFF_UP = 4l << 20;
constexpr long OFF_XC = 20l << 20;
constexpr long OFF_HS = 24l << 20;
constexpr long OFF_H  = 28l << 20;
constexpr long OFF_X1 = 36l << 20;
constexpr long OFF_SM = 40l << 20;

DEV_INLINE float wave_reduce_sum(float v) {
#pragma unroll
  for (int o = 32; o > 0; o >>= 1) v += __shfl_xor(v, o);
  return v;
}

DEV_INLINE float silu_f(float x) { return x / (1.f + expf(-x)); }
DEV_INLINE float selu_f(float x) {
  return 1.0507009873554805f * (x > 0.f ? x : 1.6732632423543772f * (expf(x) - 1.f));
}

DEV_INLINE unsigned short f2bf(float f) {  // round-to-nearest-even
  unsigned u = __float_as_uint(f);
  return (unsigned short)((u + 0x7fffu + ((u >> 16) & 1u)) >> 16);
}
DEV_INLINE float bf_lo(unsigned u) { return __uint_as_float(u << 16); }
DEV_INLINE float bf_hi(unsigned u) { return __uint_as_float(u & 0xffff0000u); }

// ---------------------------------------------------------------------------
// LayerNorm over D=1024 (one row per block, 256 threads), optional SELU.
// ---------------------------------------------------------------------------
__global__ __launch_bounds__(256) void ln1024_kernel(
    const float* __restrict__ in, const float* __restrict__ w,
    float* __restrict__ out, int applySelu) {
  __shared__ float sred[8];
  const int n = blockIdx.x, t = threadIdx.x;
  const long base = (long)n * 1024 + t * 4;
  float4 v = *(const float4*)&in[base];
  float s = v.x + v.y + v.z + v.w;
  s = wave_reduce_sum(s);
  const int wid = t >> 6;
  if ((t & 63) == 0) sred[wid] = s;
  __syncthreads();
  const float mu = (sred[0] + sred[1] + sred[2] + sred[3]) * (1.f / 1024.f);
  float4 d;
  d.x = v.x - mu; d.y = v.y - mu; d.z = v.z - mu; d.w = v.w - mu;
  float sq = d.x * d.x + d.y * d.y + d.z * d.z + d.w * d.w;
  sq = wave_reduce_sum(sq);
  if ((t & 63) == 0) sred[4 + wid] = sq;
  __syncthreads();
  const float var = (sred[4] + sred[5] + sred[6] + sred[7]) * (1.f / 1024.f);
  const float rstd = rsqrtf(var + 1e-5f);
  const float4 w4 = *(const float4*)&w[t * 4];
  float4 o4;
  o4.x = d.x * rstd * w4.x; o4.y = d.y * rstd * w4.y;
  o4.z = d.z * rstd * w4.z; o4.w = d.w * rstd * w4.w;
  if (applySelu) {
    o4.x = selu_f(o4.x); o4.y = selu_f(o4.y); o4.z = selu_f(o4.z); o4.w = selu_f(o4.w);
  }
  *(float4*)&out[base] = o4;
}

// ---------------------------------------------------------------------------
// Tiled SGEMM: C[m,n] = sum_k A[m,k]*B[k,n] (+ Res). 128x128x8 tile, 256 thr,
// 8x8 micro-tile. WT=false: W is (K,N) row-major. WT=true: W is (N,K).
// blockIdx.z batches heads via aZ/wZ/cZ element offsets.
// ---------------------------------------------------------------------------
template <bool WT>
__global__ __launch_bounds__(256) void gemm_kernel(
    const float* __restrict__ A, int lda, long aZ,
    const float* __restrict__ W, int ldw, long wZ,
    const float* __restrict__ Res, int ldr, long rZ,
    float* __restrict__ C, int ldc, long cZ,
    int M, int N, int Kd) {
  __shared__ float As[8][128];
  __shared__ float Bs[8][132];
  const int bn = blockIdx.x * 128;
  const int bm = blockIdx.y * 128;
  A += (long)blockIdx.z * aZ;
  W += (long)blockIdx.z * wZ;
  C += (long)blockIdx.z * cZ;
  const float* Rp = Res ? Res + (long)blockIdx.z * rZ : nullptr;
  const int t = threadIdx.x;
  const int tx = t & 15, ty = t >> 4;

  float acc[8][8] = {};

  const int ar = t >> 1, ak = (t & 1) * 4;
  for (int k0 = 0; k0 < Kd; k0 += 8) {
    const float4 av = *(const float4*)&A[(long)(bm + ar) * lda + k0 + ak];
    float4 bv;
    int bk, bn4, bnr, bk4;
    if (!WT) {
      bk = t >> 5; bn4 = (t & 31) << 2;
      bv = *(const float4*)&W[(long)(k0 + bk) * ldw + bn + bn4];
    } else {
      bnr = t >> 1; bk4 = (t & 1) * 4;
      bv = *(const float4*)&W[(long)(bn + bnr) * ldw + k0 + bk4];
    }
    As[ak + 0][ar] = av.x; As[ak + 1][ar] = av.y;
    As[ak + 2][ar] = av.z; As[ak + 3][ar] = av.w;
    if (!WT) {
      *(float4*)&Bs[bk][bn4] = bv;
    } else {
      Bs[bk4 + 0][bnr] = bv.x; Bs[bk4 + 1][bnr] = bv.y;
      Bs[bk4 + 2][bnr] = bv.z; Bs[bk4 + 3][bnr] = bv.w;
    }
    __syncthreads();
#pragma unroll
    for (int kk = 0; kk < 8; ++kk) {
      float a0[8], b0[8];
      *(float4*)&a0[0] = *(const float4*)&As[kk][ty * 8];
      *(float4*)&a0[4] = *(const float4*)&As[kk][ty * 8 + 4];
      *(float4*)&b0[0] = *(const float4*)&Bs[kk][tx * 8];
      *(float4*)&b0[4] = *(const float4*)&Bs[kk][tx * 8 + 4];
#pragma unroll
      for (int i = 0; i < 8; ++i)
#pragma unroll
        for (int j = 0; j < 8; ++j) acc[i][j] += a0[i] * b0[j];
    }
    __syncthreads();
  }

  const int row0 = bm + ty * 8, col0 = bn + tx * 8;
#pragma unroll
  for (int i = 0; i < 8; ++i) {
#pragma unroll
    for (int jq = 0; jq < 8; jq += 4) {
      float4 o;
      o.x = acc[i][jq + 0]; o.y = acc[i][jq + 1];
      o.z = acc[i][jq + 2]; o.w = acc[i][jq + 3];
      if (Rp) {
        const float4 r4 = *(const float4*)&Rp[(long)(row0 + i) * ldr + col0 + jq];
        o.x += r4.x; o.y += r4.y; o.z += r4.z; o.w += r4.w;
      }
      *(float4*)&C[(long)(row0 + i) * ldc + col0 + jq] = o;
    }
  }
}

// ---------------------------------------------------------------------------
// Depthwise causal conv1d (K=4) + SiLU. One float4 channel-group per thread.
// ---------------------------------------------------------------------------
__global__ __launch_bounds__(256) void conv_silu_kernel(
    const float* __restrict__ in, int ld_in,
    const float* __restrict__ w, const float* __restrict__ bias,
    float* __restrict__ out, int ld_out, int C) {
  const int idx = blockIdx.x * 256 + threadIdx.x;
  const int gpr = C >> 2;
  const int n = idx / gpr;
  const int c = (idx - n * gpr) << 2;
  const int s = n & 1023;
  float4 acc = *(const float4*)&bias[c];
  const float* wc = &w[c * 4];
#pragma unroll
  for (int tap = 0; tap < 4; ++tap) {
    const int sp = s - 3 + tap;
    if (sp >= 0) {
      const float4 xv = *(const float4*)&in[(long)(n - 3 + tap) * ld_in + c];
      acc.x += xv.x * wc[0 + tap];
      acc.y += xv.y * wc[4 + tap];
      acc.z += xv.z * wc[8 + tap];
      acc.w += xv.w * wc[12 + tap];
    }
  }
  acc.x = silu_f(acc.x); acc.y = silu_f(acc.y);
  acc.z = silu_f(acc.z); acc.w = silu_f(acc.w);
  *(float4*)&out[(long)n * ld_out + c] = acc;
}

// ---------------------------------------------------------------------------
// Fold the 4x4 block-diagonal q/k/v maps into Wig/Wfg.
// ---------------------------------------------------------------------------
__global__ __launch_bounds__(256) void wtilde_kernel(
    const float* __restrict__ Wq, const float* __restrict__ Wk,
    const float* __restrict__ Wv, const float* __restrict__ Wig,
    const float* __restrict__ Wfg,
    float* __restrict__ wqk_ig, float* __restrict__ wv_ig,
    float* __restrict__ wqk_fg, float* __restrict__ wv_fg) {
  const int idx = blockIdx.x * 256 + threadIdx.x;  // 8192
  const int c = idx >> 2, hm = idx & 3;
  const int bk = c >> 2, i = c & 3;
  float sqk_i = 0, sv_i = 0, sqk_f = 0, sv_f = 0;
#pragma unroll
  for (int o = 0; o < 4; ++o) {
    const float wq = Wq[(bk * 4 + o) * 4 + i];
    const float wk = Wk[(bk * 4 + o) * 4 + i];
    const float wv = Wv[(bk * 4 + o) * 4 + i];
    const int rq = bk * 4 + o;
    sqk_i += wq * Wig[rq * 4 + hm] + wk * Wig[(2048 + rq) * 4 + hm];
    sv_i  += wv * Wig[(4096 + rq) * 4 + hm];
    sqk_f += wq * Wfg[rq * 4 + hm] + wk * Wfg[(2048 + rq) * 4 + hm];
    sv_f  += wv * Wfg[(4096 + rq) * 4 + hm];
  }
  wqk_ig[idx] = sqk_i; wv_ig[idx] = sv_i;
  wqk_fg[idx] = sqk_f; wv_fg[idx] = sv_f;
}

// ---------------------------------------------------------------------------
// ig/fg: per token, 8 dot products of length 4096 (xc part + xi part).
// ---------------------------------------------------------------------------
__global__ __launch_bounds__(256) void igfg_kernel(
    const float* __restrict__ xc, const float* __restrict__ up,
    const float* __restrict__ wqk_ig, const float* __restrict__ wv_ig,
    const float* __restrict__ wqk_fg, const float* __restrict__ wv_fg,
    const float* __restrict__ big, const float* __restrict__ bfg,
    float* __restrict__ ig, float* __restrict__ fg) {
  __shared__ float red[4][8];
  const int n = blockIdx.x, t = threadIdx.x;
  float ai[4] = {0, 0, 0, 0}, af[4] = {0, 0, 0, 0};
  for (int c = t; c < 2048; c += 256) {
    const float xcv = xc[(long)n * 2048 + c];
    const float xiv = up[(long)n * 4096 + c];
    const float4 wiq = *(const float4*)&wqk_ig[c * 4];
    const float4 wiv = *(const float4*)&wv_ig[c * 4];
    const float4 wfq = *(const float4*)&wqk_fg[c * 4];
    const float4 wfv = *(const float4*)&wv_fg[c * 4];
    ai[0] += xcv * wiq.x + xiv * wiv.x;
    ai[1] += xcv * wiq.y + xiv * wiv.y;
    ai[2] += xcv * wiq.z + xiv * wiv.z;
    ai[3] += xcv * wiq.w + xiv * wiv.w;
    af[0] += xcv * wfq.x + xiv * wfv.x;
    af[1] += xcv * wfq.y + xiv * wfv.y;
    af[2] += xcv * wfq.z + xiv * wfv.z;
    af[3] += xcv * wfq.w + xiv * wfv.w;
  }
#pragma unroll
  for (int j = 0; j < 4; ++j) {
    ai[j] = wave_reduce_sum(ai[j]);
    af[j] = wave_reduce_sum(af[j]);
  }
  const int wid = t >> 6;
  if ((t & 63) == 0) {
#pragma unroll
    for (int j = 0; j < 4; ++j) { red[wid][j] = ai[j]; red[wid][4 + j] = af[j]; }
  }
  __syncthreads();
  if (t < 8) {
    const float v = red[0][t] + red[1][t] + red[2][t] + red[3][t];
    const int b = n >> 10, s = n & 1023;
    if (t < 4) ig[((long)b * 4 + t) * 1024 + s] = v + big[t];
    else       fg[((long)b * 4 + (t - 4)) * 1024 + s] = v + bfg[t - 4];
  }
}

// ---------------------------------------------------------------------------
// lfc = cumsum(log_sigmoid(fg)) over S per (b,h). Hillis-Steele in LDS.
// ---------------------------------------------------------------------------
__global__ __launch_bounds__(1024) void lfc_kernel(
    const float* __restrict__ fg, float* __restrict__ lfc) {
  __shared__ float sh[1024];
  const int bh = blockIdx.x, t = threadIdx.x;
  const float x = fg[(long)bh * 1024 + t];
  sh[t] = fminf(x, 0.f) - log1pf(expf(-fabsf(x)));
  __syncthreads();
  for (int off = 1; off < 1024; off <<= 1) {
    const float add = (t >= off) ? sh[t - off] : 0.f;
    __syncthreads();
    sh[t] += add;
    __syncthreads();
  }
  lfc[(long)bh * 1024 + t] = sh[t];
}

// ---------------------------------------------------------------------------
// v = headwise(xi, Wv) in place over the xi region of `up`.
// ---------------------------------------------------------------------------
__global__ __launch_bounds__(256) void hv_inplace_kernel(
    float* __restrict__ up, const float* __restrict__ Wv) {
  const int idx = blockIdx.x * 256 + threadIdx.x;  // Ntok*512
  const int n = idx >> 9, bk = idx & 511;
  const long a = (long)n * 4096 + (bk << 2);
  const float4 xv = *(const float4*)&up[a];
  const float* wb = &Wv[bk << 4];
  float4 o;
  o.x = xv.x * wb[0]  + xv.y * wb[1]  + xv.z * wb[2]  + xv.w * wb[3];
  o.y = xv.x * wb[4]  + xv.y * wb[5]  + xv.z * wb[6]  + xv.w * wb[7];
  o.z = xv.x * wb[8]  + xv.y * wb[9]  + xv.z * wb[10] + xv.w * wb[11];
  o.w = xv.x * wb[12] + xv.y * wb[13] + xv.z * wb[14] + xv.w * wb[15];
  *(float4*)&up[a] = o;
}

// ---------------------------------------------------------------------------
// mLSTM parallel, flash-style. Grid (32 rowblocks, 16 bh), 256 threads.
// ---------------------------------------------------------------------------
__global__ __launch_bounds__(256) void mlstm_attn_kernel(
    const float* __restrict__ xc, const float* __restrict__ up,
    const float* __restrict__ Wq, const float* __restrict__ Wk,
    const float* __restrict__ lfc, const float* __restrict__ igv,
    float* __restrict__ hout) {
  __shared__ float q_s[32][516];
  __shared__ float kv_s[32][516];
  __shared__ float p_s[32][36];
  __shared__ float lfci_s[32], lfcj_s[32], igj_s[32];
  const int t = threadIdx.x;
  const int ti = t >> 5, tj = t & 31;
  const int i0 = blockIdx.x * 32;
  const int bh = blockIdx.y;
  const int b = bh >> 2, h = bh & 3;
  const float kscale = 0.04419417382415922f;  // 512^-0.5

  for (int idx = t; idx < 32 * 128; idx += 256) {
    const int r = idx >> 7, g = idx & 127;
    const float4 xv =
        *(const float4*)&xc[((long)(b * 1024 + i0 + r)) * 2048 + h * 512 + (g << 2)];
    const float* wb = Wq + ((h * 128 + g) << 4);
    float4 q4;
    q4.x = xv.x * wb[0]  + xv.y * wb[1]  + xv.z * wb[2]  + xv.w * wb[3];
    q4.y = xv.x * wb[4]  + xv.y * wb[5]  + xv.z * wb[6]  + xv.w * wb[7];
    q4.z = xv.x * wb[8]  + xv.y * wb[9]  + xv.z * wb[10] + xv.w * wb[11];
    q4.w = xv.x * wb[12] + xv.y * wb[13] + xv.z * wb[14] + xv.w * wb[15];
    *(float4*)&q_s[r][g << 2] = q4;
  }
  if (t < 32) lfci_s[t] = lfc[(long)bh * 1024 + i0 + t];

  const int r0 = ti * 4;
  float m_run[4], ssum[4], accv[4][16];
#pragma unroll
  for (int e = 0; e < 4; ++e) {
    m_run[e] = -INFINITY; ssum[e] = 0.f;
#pragma unroll
    for (int u = 0; u < 16; ++u) accv[e][u] = 0.f;
  }

  for (int j0 = 0; j0 <= i0; j0 += 32) {
    __syncthreads();
    for (int idx = t; idx < 32 * 128; idx += 256) {
      const int r = idx >> 7, g = idx & 127;
      const float4 xv =
          *(const float4*)&xc[((long)(b * 1024 + j0 + r)) * 2048 + h * 512 + (g << 2)];
      const float* wb = Wk + ((h * 128 + g) << 4);
      float4 k4;
      k4.x = (xv.x * wb[0]  + xv.y * wb[1]  + xv.z * wb[2]  + xv.w * wb[3])  * kscale;
      k4.y = (xv.x * wb[4]  + xv.y * wb[5]  + xv.z * wb[6]  + xv.w * wb[7])  * kscale;
      k4.z = (xv.x * wb[8]  + xv.y * wb[9]  + xv.z * wb[10] + xv.w * wb[11]) * kscale;
      k4.w = (xv.x * wb[12] + xv.y * wb[13] + xv.z * wb[14] + xv.w * wb[15]) * kscale;
      *(float4*)&kv_s[r][g << 2] = k4;
    }
    if (t < 32) {
      lfcj_s[t] = lfc[(long)bh * 1024 + j0 + t];
      igj_s[t] = igv[(long)bh * 1024 + j0 + t];
    }
    __syncthreads();

    float sv[4] = {0.f, 0.f, 0.f, 0.f};
#pragma unroll 2
    for (int d = 0; d < 512; d += 4) {
      const float4 kv = *(const float4*)&kv_s[tj][d];
#pragma unroll
      for (int e = 0; e < 4; ++e) {
        const float4 qv = *(const float4*)&q_s[r0 + e][d];
        sv[e] += qv.x * kv.x + qv.y * kv.y + qv.z * kv.z + qv.w * kv.w;
      }
    }
    const float lfcj = lfcj_s[tj], igj = igj_s[tj];
    float mt[4], logd[4];
    bool valid[4];
#pragma unroll
    for (int e = 0; e < 4; ++e) {
      valid[e] = (j0 + tj) <= (i0 + r0 + e);
      logd[e] = lfci_s[r0 + e] - lfcj + igj;
      mt[e] = valid[e] ? logd[e] : -INFINITY;
    }
#pragma unroll
    for (int o = 16; o > 0; o >>= 1) {
#pragma unroll
      for (int e = 0; e < 4; ++e) mt[e] = fmaxf(mt[e], __shfl_xor(mt[e], o));
    }
    float p[4];
#pragma unroll
    for (int e = 0; e < 4; ++e) {
      const float mn = fmaxf(m_run[e], mt[e]);
      const float scale = __expf(m_run[e] - mn);
      m_run[e] = mn;
      p[e] = valid[e] ? sv[e] * __expf(logd[e] - mn) : 0.f;
      float ps = p[e];
#pragma unroll
      for (int o = 16; o > 0; o >>= 1) ps += __shfl_xor(ps, o);
      ssum[e] = ssum[e] * scale + ps;
#pragma unroll
      for (int u = 0; u < 16; ++u) accv[e][u] *= scale;
      p_s[r0 + e][tj] = p[e];
    }
    __syncthreads();

    for (int idx = t; idx < 32 * 128; idx += 256) {
      const int r = idx >> 7, g = idx & 127;
      const float4 vv =
          *(const float4*)&up[((long)(b * 1024 + j0 + r)) * 4096 + h * 512 + (g << 2)];
      *(float4*)&kv_s[r][g << 2] = vv;
    }
    __syncthreads();

#pragma unroll 2
    for (int j = 0; j < 32; ++j) {
      const float pj0 = p_s[r0 + 0][j];
      const float pj1 = p_s[r0 + 1][j];
      const float pj2 = p_s[r0 + 2][j];
      const float pj3 = p_s[r0 + 3][j];
#pragma unroll
      for (int u = 0; u < 16; ++u) {
        const float vv = kv_s[j][tj + (u << 5)];
        accv[0][u] += pj0 * vv;
        accv[1][u] += pj1 * vv;
        accv[2][u] += pj2 * vv;
        accv[3][u] += pj3 * vv;
      }
    }
  }

#pragma unroll
  for (int e = 0; e < 4; ++e) {
    const float norm = fmaxf(fabsf(ssum[e]), __expf(-m_run[e]));
    const float inv = 1.f / (norm + 1e-6f);
    const long rowbase = ((long)(b * 1024 + i0 + r0 + e)) * 2048 + h * 512;
#pragma unroll
    for (int u = 0; u < 16; ++u) hout[rowbase + tj + (u << 5)] = accv[e][u] * inv;
  }
}

// ---------------------------------------------------------------------------
// Block-0 epilogue: per-head LN of h (DH=512), then (hn + skip*xc)*silu(z).
// ---------------------------------------------------------------------------
__global__ __launch_bounds__(128) void mhgate_kernel(
    float* __restrict__ hbuf, const float* __restrict__ mhw,
    const float* __restrict__ skip, const float* __restrict__ xc,
    const float* __restrict__ up) {
  __shared__ float sred[4];
  const int nh = blockIdx.x, t = threadIdx.x;
  const int n = nh >> 2, hd = nh & 3;
  const long base = (long)n * 2048 + hd * 512 + t * 4;
  const float4 v = *(const float4*)&hbuf[base];
  float s = wave_reduce_sum(v.x + v.y + v.z + v.w);
  if ((t & 63) == 0) sred[t >> 6] = s;
  __syncthreads();
  const float mu = (sred[0] + sred[1]) * (1.f / 512.f);
  float4 d;
  d.x = v.x - mu; d.y = v.y - mu; d.z = v.z - mu; d.w = v.w - mu;
  float sq = wave_reduce_sum(d.x * d.x + d.y * d.y + d.z * d.z + d.w * d.w);
  if ((t & 63) == 0) sred[2 + (t >> 6)] = sq;
  __syncthreads();
  const float rstd = rsqrtf((sred[2] + sred[3]) * (1.f / 512.f) + 1e-5f);
  const int ch = hd * 512 + t * 4;
  const float4 w4 = *(const float4*)&mhw[ch];
  const float4 sk4 = *(const float4*)&skip[ch];
  const float4 xc4 = *(const float4*)&xc[(long)n * 2048 + ch];
  const float4 z4 = *(const float4*)&up[(long)n * 4096 + 2048 + ch];
  float4 o;
  o.x = (d.x * rstd * w4.x + sk4.x * xc4.x) * silu_f(z4.x);
  o.y = (d.y * rstd * w4.y + sk4.y * xc4.y) * silu_f(z4.y);
  o.z = (d.z * rstd * w4.z + sk4.z * xc4.z) * silu_f(z4.z);
  o.w = (d.w * rstd * w4.w + sk4.w * xc4.w) * silu_f(z4.w);
  *(float4*)&hbuf[base] = o;
}

// ---------------------------------------------------------------------------
// Pack R (NH_S=4, 256 rows, 1024 cols fp32) -> bf16, 4 consecutive rows per
// uint2 per column: Rp[((hd*64 + d4)*1024 + col)] = {bf(r0)|bf(r1)<<16,
// bf(r2)|bf(r3)<<16}. Runs every launch (stateless), ~30 us.
// ---------------------------------------------------------------------------
__global__ __launch_bounds__(256) void rpack_kernel(
    const float* __restrict__ R, uint2* __restrict__ Rp) {
  const int idx = blockIdx.x * 256 + threadIdx.x;  // 262144
  const int hd = idx >> 16, rem = idx & 65535;
  const int d4 = rem >> 10, col = rem & 1023;
  const float* p = R + ((long)(hd * 256 + d4 * 4)) * 1024 + col;
  uint2 o;
  o.x = (unsigned)f2bf(p[0])    | ((unsigned)f2bf(p[1024]) << 16);
  o.y = (unsigned)f2bf(p[2048]) | ((unsigned)f2bf(p[3072]) << 16);
  Rp[idx] = o;
}

// ---------------------------------------------------------------------------
// sLSTM sequential scan. One block (1024 threads) per (b,h).
// Thread t owns recurrent output column t; per step streams its bf16-packed
// R column (64 x uint2 = 512 B) from L2, unpacks, FMAs against LDS-broadcast
// h. Threads <256 own channel state + update. Per-CU bytes/step halved vs
// the fp32 R1 version (8.8 us/step measured -> ~4.4 predicted).
// ---------------------------------------------------------------------------
__global__ __launch_bounds__(1024) void slstm_scan_kernel(
    const float* __restrict__ gi, const float* __restrict__ gf,
    const float* __restrict__ gz, const float* __restrict__ go,
    const uint2* __restrict__ Rp, const float* __restrict__ bias,
    float* __restrict__ hsout) {
  __shared__ float h_cur[256];
  __shared__ float ry[1024];
  const int t = threadIdx.x;
  const int b = blockIdx.x >> 2, hd = blockIdx.x & 3;
  const uint2* Rc = Rp + (long)hd * 65536 + t;  // [d4][col], stride 1024
  float c = 0.f, nn = 0.f, m = 0.f;
  float bi = 0, bf = 0, bz = 0, bo = 0;
  if (t < 256) {
    h_cur[t] = 0.f;
    bi = bias[(hd * 4 + 0) * 256 + t];
    bf = bias[(hd * 4 + 1) * 256 + t];
    bz = bias[(hd * 4 + 2) * 256 + t];
    bo = bias[(hd * 4 + 3) * 256 + t];
  }
  __syncthreads();
  for (int s = 0; s < 1024; ++s) {
    float acc = 0.f;
#pragma unroll 8
    for (int d4 = 0; d4 < 64; ++d4) {
      const uint2 pk = Rc[d4 * 1024];
      const float4 h4 = *(const float4*)&h_cur[d4 * 4];
      acc += h4.x * bf_lo(pk.x) + h4.y * bf_hi(pk.x) +
             h4.z * bf_lo(pk.y) + h4.w * bf_hi(pk.y);
    }
    ry[t] = acc;
    __syncthreads();
    if (t < 256) {
      const long pb = ((long)(b * 1024 + s)) * 1024 + hd * 256 + t;
      const float ir = gi[pb] + ry[t] + bi;
      const float fr = gf[pb] + ry[256 + t] + bf;
      const float zr = gz[pb] + ry[512 + t] + bz;
      const float og = go[pb] + ry[768 + t] + bo;
      const float lsf = fminf(fr, 0.f) - log1pf(expf(-fabsf(fr)));
      const float lfm = m + lsf;
      const float mn = fmaxf(ir, lfm);
      const float igate = expf(ir - mn);
      const float fgate = expf(lfm - mn);
      c = fgate * c + igate * tanhf(zr);
      nn = fgate * nn + igate;
      const float hv = (1.f / (1.f + expf(-og))) * (c / (nn + 1e-6f));
      m = mn;
      h_cur[t] = hv;
      hsout[pb] = hv;
    }
    __syncthreads();
  }
}

// ---------------------------------------------------------------------------
// sLSTM epilogue: x2 = x1 + mh_layernorm(hs) * w.
// ---------------------------------------------------------------------------
__global__ __launch_bounds__(64) void mhres_kernel(
    const float* __restrict__ hs, const float* __restrict__ w,
    const float* __restrict__ x1, float* __restrict__ x2) {
  const int nh = blockIdx.x, t = threadIdx.x;
  const int n = nh >> 2, hd = nh & 3;
  const long base = (long)n * 1024 + hd * 256 + t * 4;
  const float4 v = *(const float4*)&hs[base];
  const float mu = wave_reduce_sum(v.x + v.y + v.z + v.w) * (1.f / 256.f);
  float4 d;
  d.x = v.x - mu; d.y = v.y - mu; d.z = v.z - mu; d.w = v.w - mu;
  const float var =
      wave_reduce_sum(d.x * d.x + d.y * d.y + d.z * d.z + d.w * d.w) * (1.f / 256.f);
  const float rstd = rsqrtf(var + 1e-5f);
  const float4 w4 = *(const float4*)&w[hd * 256 + t * 4];
  const float4 r4 = *(const float4*)&x1[base];
  float4 o;
  o.x = r4.x + d.x * rstd * w4.x;
  o.y = r4.y + d.y * rstd * w4.y;
  o.z = r4.z + d.z * rstd * w4.z;
  o.w = r4.w + d.w * rstd * w4.w;
  *(float4*)&x2[base] = o;
}

// ---------------------------------------------------------------------------
// GeGLU (tanh-approx gelu), in place over g.
// ---------------------------------------------------------------------------
__global__ __launch_bounds__(256) void geglu_kernel(float* __restrict__ ffn) {
  const int idx = blockIdx.x * 256 + threadIdx.x;
  const int n = idx / 1344, j = idx % 1344;
  const long base = (long)n * 2688;
  const float g = ffn[base + j];
  const float u = ffn[base + 1344 + j];
  const float t3 = 0.7978845608028654f * (g + 0.044715f * g * g * g);
  ffn[base + j] = 0.5f * g * (1.f + tanhf(t3)) * u;
}

// ---------------------------------------------------------------------------
// Column mean over S.
// ---------------------------------------------------------------------------
__global__ __launch_bounds__(256) void colmean_kernel(
    const float* __restrict__ tmp, float* __restrict__ feat) {
  const int b = blockIdx.x >> 2;
  const int ch = ((blockIdx.x & 3) << 8) + threadIdx.x;
  const float* p = tmp + (long)b * 1024 * 1024 + ch;
  float s = 0.f;
#pragma unroll 4
  for (int si = 0; si < 1024; ++si) s += p[(long)si * 1024];
  feat[b * 1024 + ch] = s * (1.f / 1024.f);
}

// ---------------------------------------------------------------------------
// Classification heads.
// ---------------------------------------------------------------------------
__global__ __launch_bounds__(256) void head_kernel(
    const float* __restrict__ feat, const float* __restrict__ We,
    const float* __restrict__ be, const float* __restrict__ Ws,
    const float* __restrict__ bs, float* __restrict__ out) {
  __shared__ float sred[4];
  const int o = blockIdx.x, t = threadIdx.x;
  const int b = o / 10, j = o % 10;
  const float* wcol;
  int ld;
  float bias;
  if (j < 7) { wcol = We + j; ld = 7; bias = be[j]; }
  else       { wcol = Ws + (j - 7); ld = 3; bias = bs[j - 7]; }
  float s = 0.f;
  for (int d = t; d < 1024; d += 256) s += feat[b * 1024 + d] * wcol[d * ld];
  s = wave_reduce_sum(s);
  if ((t & 63) == 0) sred[t >> 6] = s;
  __syncthreads();
  if (t == 0) out[o] = sred[0] + sred[1] + sred[2] + sred[3] + bias;
}

// ===========================================================================
extern "C" void kernel_launch(void* const* d_in, const int* in_sizes, int n_in,
                              void* d_out, int out_size, void* d_ws, size_t ws_size,
                              hipStream_t stream) {
  (void)in_sizes; (void)n_in; (void)out_size; (void)ws_size;
  const float* x        = (const float*)d_in[0];
  const float* m_ln_w   = (const float*)d_in[1];
  const float* m_Wup    = (const float*)d_in[2];
  const float* m_conv_w = (const float*)d_in[3];
  const float* m_conv_b = (const float*)d_in[4];
  const float* m_Wq     = (const float*)d_in[5];
  const float* m_Wk     = (const float*)d_in[6];
  const float* m_Wv     = (const float*)d_in[7];
  const float* m_Wig    = (const float*)d_in[8];
  const float* m_big    = (const float*)d_in[9];
  const float* m_Wfg    = (const float*)d_in[10];
  const float* m_bfg    = (const float*)d_in[11];
  const float* m_mhln_w = (const float*)d_in[12];
  const float* m_skip   = (const float*)d_in[13];
  const float* m_Wdown  = (const float*)d_in[14];
  const float* s_ln_w   = (const float*)d_in[15];
  const float* s_conv_w = (const float*)d_in[16];
  const float* s_conv_b = (const float*)d_in[17];
  const float* s_Wi     = (const float*)d_in[18];
  const float* s_Wf     = (const float*)d_in[19];
  const float* s_Wz     = (const float*)d_in[20];
  const float* s_Wo     = (const float*)d_in[21];
  const float* s_R      = (const float*)d_in[22];
  const float* s_b      = (const float*)d_in[23];
  const float* s_mhln_w = (const float*)d_in[24];
  const float* s_ffn_ln_w = (const float*)d_in[25];
  const float* s_Wup    = (const float*)d_in[26];
  const float* s_Wdown2 = (const float*)d_in[27];
  const float* post_ln_w = (const float*)d_in[28];
  const float* h_We     = (const float*)d_in[29];
  const float* h_be     = (const float*)d_in[30];
  const float* h_Ws     = (const float*)d_in[31];
  const float* h_bs     = (const float*)d_in[32];
  float* out = (float*)d_out;
  float* ws = (float*)d_ws;

  float* xn = ws + OFF_XN;
  float* up = ws + OFF_UP;
  float* xc = ws + OFF_XC;
  float* hsbuf = ws + OFF_HS;
  float* hb = ws + OFF_H;
  float* x1 = ws + OFF_X1;
  float* wqk_ig = ws + OFF_SM;
  float* wv_ig  = wqk_ig + 8192;
  float* wqk_fg = wqk_ig + 16384;
  float* wv_fg  = wqk_ig + 24576;
  float* igb    = ws + OFF_SM + 32768;
  float* fgb    = igb + 16384;
  float* lfcb   = igb + 32768;
  float* feat   = igb + 49152;

  // ---- block 0: mLSTM ----
  ln1024_kernel<<<4096, 256, 0, stream>>>(x, m_ln_w, xn, 0);
  gemm_kernel<false><<<dim3(32, 32, 1), 256, 0, stream>>>(
      xn, 1024, 0, m_Wup, 4096, 0, nullptr, 0, 0, up, 4096, 0, 4096, 4096, 1024);
  conv_silu_kernel<<<(4096 * 512) / 256, 256, 0, stream>>>(
      up, 4096, m_conv_w, m_conv_b, xc, 2048, 2048);
  wtilde_kernel<<<32, 256, 0, stream>>>(m_Wq, m_Wk, m_Wv, m_Wig, m_Wfg,
                                        wqk_ig, wv_ig, wqk_fg, wv_fg);
  igfg_kernel<<<4096, 256, 0, stream>>>(xc, up, wqk_ig, wv_ig, wqk_fg, wv_fg,
                                        m_big, m_bfg, igb, fgb);
  lfc_kernel<<<16, 1024, 0, stream>>>(fgb, lfcb);
  hv_inplace_kernel<<<8192, 256, 0, stream>>>(up, m_Wv);
  mlstm_attn_kernel<<<dim3(32, 16), 256, 0, stream>>>(
      xc, up, m_Wq, m_Wk, lfcb, igb, hb);
  mhgate_kernel<<<16384, 128, 0, stream>>>(hb, m_mhln_w, m_skip, xc, up);
  gemm_kernel<false><<<dim3(8, 32, 1), 256, 0, stream>>>(
      hb, 2048, 0, m_Wdown, 1024, 0, x, 1024, 0, x1, 1024, 0, 4096, 1024, 2048);

  // ---- block 1: sLSTM ----
  ln1024_kernel<<<4096, 256, 0, stream>>>(x1, s_ln_w, xn, 0);
  conv_silu_kernel<<<(4096 * 256) / 256, 256, 0, stream>>>(
      xn, 1024, s_conv_w, s_conv_b, xc, 1024, 1024);
  float* gi = up;
  float* gf = up + (4l << 20);
  float* gz = up + (8l << 20);
  float* go = up + (12l << 20);
  gemm_kernel<true><<<dim3(2, 32, 4), 256, 0, stream>>>(
      xc, 1024, 256, s_Wi, 256, 65536, nullptr, 0, 0, gi, 1024, 256, 4096, 256, 256);
  gemm_kernel<true><<<dim3(2, 32, 4), 256, 0, stream>>>(
      xc, 1024, 256, s_Wf, 256, 65536, nullptr, 0, 0, gf, 1024, 256, 4096, 256, 256);
  gemm_kernel<true><<<dim3(2, 32, 4), 256, 0, stream>>>(
      xn, 1024, 256, s_Wz, 256, 65536, nullptr, 0, 0, gz, 1024, 256, 4096, 256, 256);
  gemm_kernel<true><<<dim3(2, 32, 4), 256, 0, stream>>>(
      xn, 1024, 256, s_Wo, 256, 65536, nullptr, 0, 0, go, 1024, 256, 4096, 256, 256);
  // xn is dead until the FFN layernorm -> reuse it for the packed R (512K fl)
  uint2* Rpacked = (uint2*)xn;
  rpack_kernel<<<1024, 256, 0, stream>>>(s_R, Rpacked);
  slstm_scan_kernel<<<16, 1024, 0, stream>>>(gi, gf, gz, go, Rpacked, s_b, hsbuf);
  mhres_kernel<<<16384, 64, 0, stream>>>(hsbuf, s_mhln_w, x1, hb);
  float* x2 = hb;

  // ---- FFN ----
  ln1024_kernel<<<4096, 256, 0, stream>>>(x2, s_ffn_ln_w, xn, 0);
  float* ffn = up;
  gemm_kernel<false><<<dim3(21, 32, 1), 256, 0, stream>>>(
      xn, 1024, 0, s_Wup, 2688, 0, nullptr, 0, 0, ffn, 2688, 0, 4096, 2688, 1024);
  geglu_kernel<<<(4096 * 1344) / 256, 256, 0, stream>>>(ffn);
  gemm_kernel<false><<<dim3(8, 32, 1), 256, 0, stream>>>(
      ffn, 2688, 0, s_Wdown2, 1024, 0, x2, 1024, 0, x1, 1024, 0, 4096, 1024, 1344);
  float* x3 = x1;

  // ---- post: LN + SELU + mean pool + heads ----
  ln1024_kernel<<<4096, 256, 0, stream>>>(x3, post_ln_w, xn, 1);
  colmean_kernel<<<16, 256, 0, stream>>>(xn, feat);
  head_kernel<<<40, 256, 0, stream>>>(feat, h_We, h_be, h_Ws, h_bs, out);
}

// Round 6
// 8001.527 us; speedup vs baseline: 2.5633x; 1.5070x over previous
//
#include <hip/hip_runtime.h>
#include <hip/hip_bf16.h>

// ============================================================================
// xLSTM audio model, fp32 (+ f16-packed sLSTM recurrent matrix, dot2 matvec).
// B=4, S=1024, D=1024, INNER=2048, NH_M=4, DH_M=512, NH_S=4, DH_S=256,
// K(conv)=4, FF_UP=1344. N = B*S = 4096 tokens.
//
// R6: scan was LDS-issue-bound (64 ds_read_b128 h-broadcasts/thread/step,
// ~12 cyc each on the one LDS pipe -> 5.1 us/step; R5's byte-halving gave
// only -5%). This round: h packed f16 in LDS (32 reads), R packed f16 pairs
// consumed by v_dot2_f32_f16 (VALU halved), next-step gate preacts
// prefetched. New floor: 512 KB/step R stream from L2 (~3.6 us/step).
// ============================================================================

#define DEV_INLINE __device__ __forceinline__

constexpr long OFF_XN = 0;
constexpr long OFF_UP = 4l << 20;
constexpr long OFF_XC = 20l << 20;
constexpr long OFF_HS = 24l << 20;
constexpr long OFF_H  = 28l << 20;
constexpr long OFF_X1 = 36l << 20;
constexpr long OFF_SM = 40l << 20;

typedef _Float16 f16x2 __attribute__((ext_vector_type(2)));

DEV_INLINE float wave_reduce_sum(float v) {
#pragma unroll
  for (int o = 32; o > 0; o >>= 1) v += __shfl_xor(v, o);
  return v;
}

DEV_INLINE float silu_f(float x) { return x / (1.f + expf(-x)); }
DEV_INLINE float selu_f(float x) {
  return 1.0507009873554805f * (x > 0.f ? x : 1.6732632423543772f * (expf(x) - 1.f));
}

DEV_INLINE float dot2u(unsigned h2, unsigned r2, float c) {
#if __has_builtin(__builtin_amdgcn_fdot2)
  return __builtin_amdgcn_fdot2(__builtin_bit_cast(f16x2, h2),
                                __builtin_bit_cast(f16x2, r2), c, false);
#else
  const f16x2 a = __builtin_bit_cast(f16x2, h2);
  const f16x2 b = __builtin_bit_cast(f16x2, r2);
  return c + (float)a[0] * (float)b[0] + (float)a[1] * (float)b[1];
#endif
}

// ---------------------------------------------------------------------------
// LayerNorm over D=1024 (one row per block, 256 threads), optional SELU.
// ---------------------------------------------------------------------------
__global__ __launch_bounds__(256) void ln1024_kernel(
    const float* __restrict__ in, const float* __restrict__ w,
    float* __restrict__ out, int applySelu) {
  __shared__ float sred[8];
  const int n = blockIdx.x, t = threadIdx.x;
  const long base = (long)n * 1024 + t * 4;
  float4 v = *(const float4*)&in[base];
  float s = v.x + v.y + v.z + v.w;
  s = wave_reduce_sum(s);
  const int wid = t >> 6;
  if ((t & 63) == 0) sred[wid] = s;
  __syncthreads();
  const float mu = (sred[0] + sred[1] + sred[2] + sred[3]) * (1.f / 1024.f);
  float4 d;
  d.x = v.x - mu; d.y = v.y - mu; d.z = v.z - mu; d.w = v.w - mu;
  float sq = d.x * d.x + d.y * d.y + d.z * d.z + d.w * d.w;
  sq = wave_reduce_sum(sq);
  if ((t & 63) == 0) sred[4 + wid] = sq;
  __syncthreads();
  const float var = (sred[4] + sred[5] + sred[6] + sred[7]) * (1.f / 1024.f);
  const float rstd = rsqrtf(var + 1e-5f);
  const float4 w4 = *(const float4*)&w[t * 4];
  float4 o4;
  o4.x = d.x * rstd * w4.x; o4.y = d.y * rstd * w4.y;
  o4.z = d.z * rstd * w4.z; o4.w = d.w * rstd * w4.w;
  if (applySelu) {
    o4.x = selu_f(o4.x); o4.y = selu_f(o4.y); o4.z = selu_f(o4.z); o4.w = selu_f(o4.w);
  }
  *(float4*)&out[base] = o4;
}

// ---------------------------------------------------------------------------
// Tiled SGEMM: C[m,n] = sum_k A[m,k]*B[k,n] (+ Res). 128x128x8 tile, 256 thr,
// 8x8 micro-tile. WT=false: W is (K,N) row-major. WT=true: W is (N,K).
// blockIdx.z batches heads via aZ/wZ/cZ element offsets.
// ---------------------------------------------------------------------------
template <bool WT>
__global__ __launch_bounds__(256) void gemm_kernel(
    const float* __restrict__ A, int lda, long aZ,
    const float* __restrict__ W, int ldw, long wZ,
    const float* __restrict__ Res, int ldr, long rZ,
    float* __restrict__ C, int ldc, long cZ,
    int M, int N, int Kd) {
  __shared__ float As[8][128];
  __shared__ float Bs[8][132];
  const int bn = blockIdx.x * 128;
  const int bm = blockIdx.y * 128;
  A += (long)blockIdx.z * aZ;
  W += (long)blockIdx.z * wZ;
  C += (long)blockIdx.z * cZ;
  const float* Rp = Res ? Res + (long)blockIdx.z * rZ : nullptr;
  const int t = threadIdx.x;
  const int tx = t & 15, ty = t >> 4;

  float acc[8][8] = {};

  const int ar = t >> 1, ak = (t & 1) * 4;
  for (int k0 = 0; k0 < Kd; k0 += 8) {
    const float4 av = *(const float4*)&A[(long)(bm + ar) * lda + k0 + ak];
    float4 bv;
    int bk, bn4, bnr, bk4;
    if (!WT) {
      bk = t >> 5; bn4 = (t & 31) << 2;
      bv = *(const float4*)&W[(long)(k0 + bk) * ldw + bn + bn4];
    } else {
      bnr = t >> 1; bk4 = (t & 1) * 4;
      bv = *(const float4*)&W[(long)(bn + bnr) * ldw + k0 + bk4];
    }
    As[ak + 0][ar] = av.x; As[ak + 1][ar] = av.y;
    As[ak + 2][ar] = av.z; As[ak + 3][ar] = av.w;
    if (!WT) {
      *(float4*)&Bs[bk][bn4] = bv;
    } else {
      Bs[bk4 + 0][bnr] = bv.x; Bs[bk4 + 1][bnr] = bv.y;
      Bs[bk4 + 2][bnr] = bv.z; Bs[bk4 + 3][bnr] = bv.w;
    }
    __syncthreads();
#pragma unroll
    for (int kk = 0; kk < 8; ++kk) {
      float a0[8], b0[8];
      *(float4*)&a0[0] = *(const float4*)&As[kk][ty * 8];
      *(float4*)&a0[4] = *(const float4*)&As[kk][ty * 8 + 4];
      *(float4*)&b0[0] = *(const float4*)&Bs[kk][tx * 8];
      *(float4*)&b0[4] = *(const float4*)&Bs[kk][tx * 8 + 4];
#pragma unroll
      for (int i = 0; i < 8; ++i)
#pragma unroll
        for (int j = 0; j < 8; ++j) acc[i][j] += a0[i] * b0[j];
    }
    __syncthreads();
  }

  const int row0 = bm + ty * 8, col0 = bn + tx * 8;
#pragma unroll
  for (int i = 0; i < 8; ++i) {
#pragma unroll
    for (int jq = 0; jq < 8; jq += 4) {
      float4 o;
      o.x = acc[i][jq + 0]; o.y = acc[i][jq + 1];
      o.z = acc[i][jq + 2]; o.w = acc[i][jq + 3];
      if (Rp) {
        const float4 r4 = *(const float4*)&Rp[(long)(row0 + i) * ldr + col0 + jq];
        o.x += r4.x; o.y += r4.y; o.z += r4.z; o.w += r4.w;
      }
      *(float4*)&C[(long)(row0 + i) * ldc + col0 + jq] = o;
    }
  }
}

// ---------------------------------------------------------------------------
// Depthwise causal conv1d (K=4) + SiLU. One float4 channel-group per thread.
// ---------------------------------------------------------------------------
__global__ __launch_bounds__(256) void conv_silu_kernel(
    const float* __restrict__ in, int ld_in,
    const float* __restrict__ w, const float* __restrict__ bias,
    float* __restrict__ out, int ld_out, int C) {
  const int idx = blockIdx.x * 256 + threadIdx.x;
  const int gpr = C >> 2;
  const int n = idx / gpr;
  const int c = (idx - n * gpr) << 2;
  const int s = n & 1023;
  float4 acc = *(const float4*)&bias[c];
  const float* wc = &w[c * 4];
#pragma unroll
  for (int tap = 0; tap < 4; ++tap) {
    const int sp = s - 3 + tap;
    if (sp >= 0) {
      const float4 xv = *(const float4*)&in[(long)(n - 3 + tap) * ld_in + c];
      acc.x += xv.x * wc[0 + tap];
      acc.y += xv.y * wc[4 + tap];
      acc.z += xv.z * wc[8 + tap];
      acc.w += xv.w * wc[12 + tap];
    }
  }
  acc.x = silu_f(acc.x); acc.y = silu_f(acc.y);
  acc.z = silu_f(acc.z); acc.w = silu_f(acc.w);
  *(float4*)&out[(long)n * ld_out + c] = acc;
}

// ---------------------------------------------------------------------------
// Fold the 4x4 block-diagonal q/k/v maps into Wig/Wfg.
// ---------------------------------------------------------------------------
__global__ __launch_bounds__(256) void wtilde_kernel(
    const float* __restrict__ Wq, const float* __restrict__ Wk,
    const float* __restrict__ Wv, const float* __restrict__ Wig,
    const float* __restrict__ Wfg,
    float* __restrict__ wqk_ig, float* __restrict__ wv_ig,
    float* __restrict__ wqk_fg, float* __restrict__ wv_fg) {
  const int idx = blockIdx.x * 256 + threadIdx.x;  // 8192
  const int c = idx >> 2, hm = idx & 3;
  const int bk = c >> 2, i = c & 3;
  float sqk_i = 0, sv_i = 0, sqk_f = 0, sv_f = 0;
#pragma unroll
  for (int o = 0; o < 4; ++o) {
    const float wq = Wq[(bk * 4 + o) * 4 + i];
    const float wk = Wk[(bk * 4 + o) * 4 + i];
    const float wv = Wv[(bk * 4 + o) * 4 + i];
    const int rq = bk * 4 + o;
    sqk_i += wq * Wig[rq * 4 + hm] + wk * Wig[(2048 + rq) * 4 + hm];
    sv_i  += wv * Wig[(4096 + rq) * 4 + hm];
    sqk_f += wq * Wfg[rq * 4 + hm] + wk * Wfg[(2048 + rq) * 4 + hm];
    sv_f  += wv * Wfg[(4096 + rq) * 4 + hm];
  }
  wqk_ig[idx] = sqk_i; wv_ig[idx] = sv_i;
  wqk_fg[idx] = sqk_f; wv_fg[idx] = sv_f;
}

// ---------------------------------------------------------------------------
// ig/fg: per token, 8 dot products of length 4096 (xc part + xi part).
// ---------------------------------------------------------------------------
__global__ __launch_bounds__(256) void igfg_kernel(
    const float* __restrict__ xc, const float* __restrict__ up,
    const float* __restrict__ wqk_ig, const float* __restrict__ wv_ig,
    const float* __restrict__ wqk_fg, const float* __restrict__ wv_fg,
    const float* __restrict__ big, const float* __restrict__ bfg,
    float* __restrict__ ig, float* __restrict__ fg) {
  __shared__ float red[4][8];
  const int n = blockIdx.x, t = threadIdx.x;
  float ai[4] = {0, 0, 0, 0}, af[4] = {0, 0, 0, 0};
  for (int c = t; c < 2048; c += 256) {
    const float xcv = xc[(long)n * 2048 + c];
    const float xiv = up[(long)n * 4096 + c];
    const float4 wiq = *(const float4*)&wqk_ig[c * 4];
    const float4 wiv = *(const float4*)&wv_ig[c * 4];
    const float4 wfq = *(const float4*)&wqk_fg[c * 4];
    const float4 wfv = *(const float4*)&wv_fg[c * 4];
    ai[0] += xcv * wiq.x + xiv * wiv.x;
    ai[1] += xcv * wiq.y + xiv * wiv.y;
    ai[2] += xcv * wiq.z + xiv * wiv.z;
    ai[3] += xcv * wiq.w + xiv * wiv.w;
    af[0] += xcv * wfq.x + xiv * wfv.x;
    af[1] += xcv * wfq.y + xiv * wfv.y;
    af[2] += xcv * wfq.z + xiv * wfv.z;
    af[3] += xcv * wfq.w + xiv * wfv.w;
  }
#pragma unroll
  for (int j = 0; j < 4; ++j) {
    ai[j] = wave_reduce_sum(ai[j]);
    af[j] = wave_reduce_sum(af[j]);
  }
  const int wid = t >> 6;
  if ((t & 63) == 0) {
#pragma unroll
    for (int j = 0; j < 4; ++j) { red[wid][j] = ai[j]; red[wid][4 + j] = af[j]; }
  }
  __syncthreads();
  if (t < 8) {
    const float v = red[0][t] + red[1][t] + red[2][t] + red[3][t];
    const int b = n >> 10, s = n & 1023;
    if (t < 4) ig[((long)b * 4 + t) * 1024 + s] = v + big[t];
    else       fg[((long)b * 4 + (t - 4)) * 1024 + s] = v + bfg[t - 4];
  }
}

// ---------------------------------------------------------------------------
// lfc = cumsum(log_sigmoid(fg)) over S per (b,h). Hillis-Steele in LDS.
// ---------------------------------------------------------------------------
__global__ __launch_bounds__(1024) void lfc_kernel(
    const float* __restrict__ fg, float* __restrict__ lfc) {
  __shared__ float sh[1024];
  const int bh = blockIdx.x, t = threadIdx.x;
  const float x = fg[(long)bh * 1024 + t];
  sh[t] = fminf(x, 0.f) - log1pf(expf(-fabsf(x)));
  __syncthreads();
  for (int off = 1; off < 1024; off <<= 1) {
    const float add = (t >= off) ? sh[t - off] : 0.f;
    __syncthreads();
    sh[t] += add;
    __syncthreads();
  }
  lfc[(long)bh * 1024 + t] = sh[t];
}

// ---------------------------------------------------------------------------
// v = headwise(xi, Wv) in place over the xi region of `up`.
// ---------------------------------------------------------------------------
__global__ __launch_bounds__(256) void hv_inplace_kernel(
    float* __restrict__ up, const float* __restrict__ Wv) {
  const int idx = blockIdx.x * 256 + threadIdx.x;  // Ntok*512
  const int n = idx >> 9, bk = idx & 511;
  const long a = (long)n * 4096 + (bk << 2);
  const float4 xv = *(const float4*)&up[a];
  const float* wb = &Wv[bk << 4];
  float4 o;
  o.x = xv.x * wb[0]  + xv.y * wb[1]  + xv.z * wb[2]  + xv.w * wb[3];
  o.y = xv.x * wb[4]  + xv.y * wb[5]  + xv.z * wb[6]  + xv.w * wb[7];
  o.z = xv.x * wb[8]  + xv.y * wb[9]  + xv.z * wb[10] + xv.w * wb[11];
  o.w = xv.x * wb[12] + xv.y * wb[13] + xv.z * wb[14] + xv.w * wb[15];
  *(float4*)&up[a] = o;
}

// ---------------------------------------------------------------------------
// mLSTM parallel, flash-style. Grid (32 rowblocks, 16 bh), 256 threads.
// ---------------------------------------------------------------------------
__global__ __launch_bounds__(256) void mlstm_attn_kernel(
    const float* __restrict__ xc, const float* __restrict__ up,
    const float* __restrict__ Wq, const float* __restrict__ Wk,
    const float* __restrict__ lfc, const float* __restrict__ igv,
    float* __restrict__ hout) {
  __shared__ float q_s[32][516];
  __shared__ float kv_s[32][516];
  __shared__ float p_s[32][36];
  __shared__ float lfci_s[32], lfcj_s[32], igj_s[32];
  const int t = threadIdx.x;
  const int ti = t >> 5, tj = t & 31;
  const int i0 = blockIdx.x * 32;
  const int bh = blockIdx.y;
  const int b = bh >> 2, h = bh & 3;
  const float kscale = 0.04419417382415922f;  // 512^-0.5

  for (int idx = t; idx < 32 * 128; idx += 256) {
    const int r = idx >> 7, g = idx & 127;
    const float4 xv =
        *(const float4*)&xc[((long)(b * 1024 + i0 + r)) * 2048 + h * 512 + (g << 2)];
    const float* wb = Wq + ((h * 128 + g) << 4);
    float4 q4;
    q4.x = xv.x * wb[0]  + xv.y * wb[1]  + xv.z * wb[2]  + xv.w * wb[3];
    q4.y = xv.x * wb[4]  + xv.y * wb[5]  + xv.z * wb[6]  + xv.w * wb[7];
    q4.z = xv.x * wb[8]  + xv.y * wb[9]  + xv.z * wb[10] + xv.w * wb[11];
    q4.w = xv.x * wb[12] + xv.y * wb[13] + xv.z * wb[14] + xv.w * wb[15];
    *(float4*)&q_s[r][g << 2] = q4;
  }
  if (t < 32) lfci_s[t] = lfc[(long)bh * 1024 + i0 + t];

  const int r0 = ti * 4;
  float m_run[4], ssum[4], accv[4][16];
#pragma unroll
  for (int e = 0; e < 4; ++e) {
    m_run[e] = -INFINITY; ssum[e] = 0.f;
#pragma unroll
    for (int u = 0; u < 16; ++u) accv[e][u] = 0.f;
  }

  for (int j0 = 0; j0 <= i0; j0 += 32) {
    __syncthreads();
    for (int idx = t; idx < 32 * 128; idx += 256) {
      const int r = idx >> 7, g = idx & 127;
      const float4 xv =
          *(const float4*)&xc[((long)(b * 1024 + j0 + r)) * 2048 + h * 512 + (g << 2)];
      const float* wb = Wk + ((h * 128 + g) << 4);
      float4 k4;
      k4.x = (xv.x * wb[0]  + xv.y * wb[1]  + xv.z * wb[2]  + xv.w * wb[3])  * kscale;
      k4.y = (xv.x * wb[4]  + xv.y * wb[5]  + xv.z * wb[6]  + xv.w * wb[7])  * kscale;
      k4.z = (xv.x * wb[8]  + xv.y * wb[9]  + xv.z * wb[10] + xv.w * wb[11]) * kscale;
      k4.w = (xv.x * wb[12] + xv.y * wb[13] + xv.z * wb[14] + xv.w * wb[15]) * kscale;
      *(float4*)&kv_s[r][g << 2] = k4;
    }
    if (t < 32) {
      lfcj_s[t] = lfc[(long)bh * 1024 + j0 + t];
      igj_s[t] = igv[(long)bh * 1024 + j0 + t];
    }
    __syncthreads();

    float sv[4] = {0.f, 0.f, 0.f, 0.f};
#pragma unroll 2
    for (int d = 0; d < 512; d += 4) {
      const float4 kv = *(const float4*)&kv_s[tj][d];
#pragma unroll
      for (int e = 0; e < 4; ++e) {
        const float4 qv = *(const float4*)&q_s[r0 + e][d];
        sv[e] += qv.x * kv.x + qv.y * kv.y + qv.z * kv.z + qv.w * kv.w;
      }
    }
    const float lfcj = lfcj_s[tj], igj = igj_s[tj];
    float mt[4], logd[4];
    bool valid[4];
#pragma unroll
    for (int e = 0; e < 4; ++e) {
      valid[e] = (j0 + tj) <= (i0 + r0 + e);
      logd[e] = lfci_s[r0 + e] - lfcj + igj;
      mt[e] = valid[e] ? logd[e] : -INFINITY;
    }
#pragma unroll
    for (int o = 16; o > 0; o >>= 1) {
#pragma unroll
      for (int e = 0; e < 4; ++e) mt[e] = fmaxf(mt[e], __shfl_xor(mt[e], o));
    }
    float p[4];
#pragma unroll
    for (int e = 0; e < 4; ++e) {
      const float mn = fmaxf(m_run[e], mt[e]);
      const float scale = __expf(m_run[e] - mn);
      m_run[e] = mn;
      p[e] = valid[e] ? sv[e] * __expf(logd[e] - mn) : 0.f;
      float ps = p[e];
#pragma unroll
      for (int o = 16; o > 0; o >>= 1) ps += __shfl_xor(ps, o);
      ssum[e] = ssum[e] * scale + ps;
#pragma unroll
      for (int u = 0; u < 16; ++u) accv[e][u] *= scale;
      p_s[r0 + e][tj] = p[e];
    }
    __syncthreads();

    for (int idx = t; idx < 32 * 128; idx += 256) {
      const int r = idx >> 7, g = idx & 127;
      const float4 vv =
          *(const float4*)&up[((long)(b * 1024 + j0 + r)) * 4096 + h * 512 + (g << 2)];
      *(float4*)&kv_s[r][g << 2] = vv;
    }
    __syncthreads();

#pragma unroll 2
    for (int j = 0; j < 32; ++j) {
      const float pj0 = p_s[r0 + 0][j];
      const float pj1 = p_s[r0 + 1][j];
      const float pj2 = p_s[r0 + 2][j];
      const float pj3 = p_s[r0 + 3][j];
#pragma unroll
      for (int u = 0; u < 16; ++u) {
        const float vv = kv_s[j][tj + (u << 5)];
        accv[0][u] += pj0 * vv;
        accv[1][u] += pj1 * vv;
        accv[2][u] += pj2 * vv;
        accv[3][u] += pj3 * vv;
      }
    }
  }

#pragma unroll
  for (int e = 0; e < 4; ++e) {
    const float norm = fmaxf(fabsf(ssum[e]), __expf(-m_run[e]));
    const float inv = 1.f / (norm + 1e-6f);
    const long rowbase = ((long)(b * 1024 + i0 + r0 + e)) * 2048 + h * 512;
#pragma unroll
    for (int u = 0; u < 16; ++u) hout[rowbase + tj + (u << 5)] = accv[e][u] * inv;
  }
}

// ---------------------------------------------------------------------------
// Block-0 epilogue: per-head LN of h (DH=512), then (hn + skip*xc)*silu(z).
// ---------------------------------------------------------------------------
__global__ __launch_bounds__(128) void mhgate_kernel(
    float* __restrict__ hbuf, const float* __restrict__ mhw,
    const float* __restrict__ skip, const float* __restrict__ xc,
    const float* __restrict__ up) {
  __shared__ float sred[4];
  const int nh = blockIdx.x, t = threadIdx.x;
  const int n = nh >> 2, hd = nh & 3;
  const long base = (long)n * 2048 + hd * 512 + t * 4;
  const float4 v = *(const float4*)&hbuf[base];
  float s = wave_reduce_sum(v.x + v.y + v.z + v.w);
  if ((t & 63) == 0) sred[t >> 6] = s;
  __syncthreads();
  const float mu = (sred[0] + sred[1]) * (1.f / 512.f);
  float4 d;
  d.x = v.x - mu; d.y = v.y - mu; d.z = v.z - mu; d.w = v.w - mu;
  float sq = wave_reduce_sum(d.x * d.x + d.y * d.y + d.z * d.z + d.w * d.w);
  if ((t & 63) == 0) sred[2 + (t >> 6)] = sq;
  __syncthreads();
  const float rstd = rsqrtf((sred[2] + sred[3]) * (1.f / 512.f) + 1e-5f);
  const int ch = hd * 512 + t * 4;
  const float4 w4 = *(const float4*)&mhw[ch];
  const float4 sk4 = *(const float4*)&skip[ch];
  const float4 xc4 = *(const float4*)&xc[(long)n * 2048 + ch];
  const float4 z4 = *(const float4*)&up[(long)n * 4096 + 2048 + ch];
  float4 o;
  o.x = (d.x * rstd * w4.x + sk4.x * xc4.x) * silu_f(z4.x);
  o.y = (d.y * rstd * w4.y + sk4.y * xc4.y) * silu_f(z4.y);
  o.z = (d.z * rstd * w4.z + sk4.z * xc4.z) * silu_f(z4.z);
  o.w = (d.w * rstd * w4.w + sk4.w * xc4.w) * silu_f(z4.w);
  *(float4*)&hbuf[base] = o;
}

// ---------------------------------------------------------------------------
// Pack R (NH_S=4, 256 rows, 1024 cols fp32) -> f16 pairs: rows 8*d8..8*d8+7
// of column col go into one uint4 (4 dwords = 4 row-pairs).
// Rp[(hd*32 + d8)*1024 + col]. ~2 MB total, repacked every launch.
// ---------------------------------------------------------------------------
__global__ __launch_bounds__(256) void rpack_kernel(
    const float* __restrict__ R, uint4* __restrict__ Rp) {
  const int idx = blockIdx.x * 256 + threadIdx.x;  // 131072
  const int hd = idx >> 15, rem = idx & 32767;
  const int d8 = rem >> 10, col = rem & 1023;
  const float* p = R + ((long)(hd * 256 + d8 * 8)) * 1024 + col;
  unsigned short hw[8];
#pragma unroll
  for (int k = 0; k < 8; ++k)
    hw[k] = __builtin_bit_cast(unsigned short, (_Float16)p[(long)k * 1024]);
  uint4 o;
  o.x = (unsigned)hw[0] | ((unsigned)hw[1] << 16);
  o.y = (unsigned)hw[2] | ((unsigned)hw[3] << 16);
  o.z = (unsigned)hw[4] | ((unsigned)hw[5] << 16);
  o.w = (unsigned)hw[6] | ((unsigned)hw[7] << 16);
  Rp[idx] = o;
}

// ---------------------------------------------------------------------------
// sLSTM sequential scan. One block (1024 threads) per (b,h).
// Thread t owns recurrent output column t. h kept f16-packed in LDS (one
// ds_read_b128 = 8 h values); R streamed as f16-pair uint4 (8 rows / 16B);
// MACs via v_dot2_f32_f16. Next-step gate preacts prefetched into registers
// to hide L3/HBM latency on the serial update path.
// ---------------------------------------------------------------------------
__global__ __launch_bounds__(1024) void slstm_scan_kernel(
    const float* __restrict__ gi, const float* __restrict__ gf,
    const float* __restrict__ gz, const float* __restrict__ go,
    const uint4* __restrict__ Rp, const float* __restrict__ bias,
    float* __restrict__ hsout) {
  __shared__ uint4 h16q[32];   // 256 f16 h values, packed
  __shared__ float ry[1024];
  const int t = threadIdx.x;
  const int b = blockIdx.x >> 2, hd = blockIdx.x & 3;
  const uint4* Rc = Rp + (long)hd * 32768 + t;  // [d8][col], stride 1024
  float c = 0.f, nn = 0.f, m = 0.f;
  float bi = 0, bf = 0, bz = 0, bo = 0;
  float gii = 0, gfv = 0, gzv = 0, gov = 0;
  if (t < 256) {
    ((_Float16*)h16q)[t] = (_Float16)0.f;
    bi = bias[(hd * 4 + 0) * 256 + t];
    bf = bias[(hd * 4 + 1) * 256 + t];
    bz = bias[(hd * 4 + 2) * 256 + t];
    bo = bias[(hd * 4 + 3) * 256 + t];
    const long pb0 = ((long)(b * 1024)) * 1024 + hd * 256 + t;
    gii = gi[pb0]; gfv = gf[pb0]; gzv = gz[pb0]; gov = go[pb0];
  }
  __syncthreads();
  for (int s = 0; s < 1024; ++s) {
    float acc = 0.f;
#pragma unroll 8
    for (int d8 = 0; d8 < 32; ++d8) {
      const uint4 rv = Rc[d8 * 1024];
      const uint4 hv = h16q[d8];
      acc = dot2u(hv.x, rv.x, acc);
      acc = dot2u(hv.y, rv.y, acc);
      acc = dot2u(hv.z, rv.z, acc);
      acc = dot2u(hv.w, rv.w, acc);
    }
    ry[t] = acc;
    // prefetch next step's gate preacts (overlaps barrier + update)
    float ni = 0, nf = 0, nz = 0, no = 0;
    if (t < 256 && s < 1023) {
      const long pb1 = ((long)(b * 1024 + s + 1)) * 1024 + hd * 256 + t;
      ni = gi[pb1]; nf = gf[pb1]; nz = gz[pb1]; no = go[pb1];
    }
    __syncthreads();
    if (t < 256) {
      const long pb = ((long)(b * 1024 + s)) * 1024 + hd * 256 + t;
      const float ir = gii + ry[t] + bi;
      const float fr = gfv + ry[256 + t] + bf;
      const float zr = gzv + ry[512 + t] + bz;
      const float og = gov + ry[768 + t] + bo;
      const float lsf = fminf(fr, 0.f) - log1pf(expf(-fabsf(fr)));
      const float lfm = m + lsf;
      const float mn = fmaxf(ir, lfm);
      const float igate = expf(ir - mn);
      const float fgate = expf(lfm - mn);
      c = fgate * c + igate * tanhf(zr);
      nn = fgate * nn + igate;
      const float hv = (1.f / (1.f + expf(-og))) * (c / (nn + 1e-6f));
      m = mn;
      ((_Float16*)h16q)[t] = (_Float16)hv;
      hsout[pb] = hv;
    }
    gii = ni; gfv = nf; gzv = nz; gov = no;
    __syncthreads();
  }
}

// ---------------------------------------------------------------------------
// sLSTM epilogue: x2 = x1 + mh_layernorm(hs) * w.
// ---------------------------------------------------------------------------
__global__ __launch_bounds__(64) void mhres_kernel(
    const float* __restrict__ hs, const float* __restrict__ w,
    const float* __restrict__ x1, float* __restrict__ x2) {
  const int nh = blockIdx.x, t = threadIdx.x;
  const int n = nh >> 2, hd = nh & 3;
  const long base = (long)n * 1024 + hd * 256 + t * 4;
  const float4 v = *(const float4*)&hs[base];
  const float mu = wave_reduce_sum(v.x + v.y + v.z + v.w) * (1.f / 256.f);
  float4 d;
  d.x = v.x - mu; d.y = v.y - mu; d.z = v.z - mu; d.w = v.w - mu;
  const float var =
      wave_reduce_sum(d.x * d.x + d.y * d.y + d.z * d.z + d.w * d.w) * (1.f / 256.f);
  const float rstd = rsqrtf(var + 1e-5f);
  const float4 w4 = *(const float4*)&w[hd * 256 + t * 4];
  const float4 r4 = *(const float4*)&x1[base];
  float4 o;
  o.x = r4.x + d.x * rstd * w4.x;
  o.y = r4.y + d.y * rstd * w4.y;
  o.z = r4.z + d.z * rstd * w4.z;
  o.w = r4.w + d.w * rstd * w4.w;
  *(float4*)&x2[base] = o;
}

// ---------------------------------------------------------------------------
// GeGLU (tanh-approx gelu), in place over g.
// ---------------------------------------------------------------------------
__global__ __launch_bounds__(256) void geglu_kernel(float* __restrict__ ffn) {
  const int idx = blockIdx.x * 256 + threadIdx.x;
  const int n = idx / 1344, j = idx % 1344;
  const long base = (long)n * 2688;
  const float g = ffn[base + j];
  const float u = ffn[base + 1344 + j];
  const float t3 = 0.7978845608028654f * (g + 0.044715f * g * g * g);
  ffn[base + j] = 0.5f * g * (1.f + tanhf(t3)) * u;
}

// ---------------------------------------------------------------------------
// Column mean over S.
// ---------------------------------------------------------------------------
__global__ __launch_bounds__(256) void colmean_kernel(
    const float* __restrict__ tmp, float* __restrict__ feat) {
  const int b = blockIdx.x >> 2;
  const int ch = ((blockIdx.x & 3) << 8) + threadIdx.x;
  const float* p = tmp + (long)b * 1024 * 1024 + ch;
  float s = 0.f;
#pragma unroll 4
  for (int si = 0; si < 1024; ++si) s += p[(long)si * 1024];
  feat[b * 1024 + ch] = s * (1.f / 1024.f);
}

// ---------------------------------------------------------------------------
// Classification heads.
// ---------------------------------------------------------------------------
__global__ __launch_bounds__(256) void head_kernel(
    const float* __restrict__ feat, const float* __restrict__ We,
    const float* __restrict__ be, const float* __restrict__ Ws,
    const float* __restrict__ bs, float* __restrict__ out) {
  __shared__ float sred[4];
  const int o = blockIdx.x, t = threadIdx.x;
  const int b = o / 10, j = o % 10;
  const float* wcol;
  int ld;
  float bias;
  if (j < 7) { wcol = We + j; ld = 7; bias = be[j]; }
  else       { wcol = Ws + (j - 7); ld = 3; bias = bs[j - 7]; }
  float s = 0.f;
  for (int d = t; d < 1024; d += 256) s += feat[b * 1024 + d] * wcol[d * ld];
  s = wave_reduce_sum(s);
  if ((t & 63) == 0) sred[t >> 6] = s;
  __syncthreads();
  if (t == 0) out[o] = sred[0] + sred[1] + sred[2] + sred[3] + bias;
}

// ===========================================================================
extern "C" void kernel_launch(void* const* d_in, const int* in_sizes, int n_in,
                              void* d_out, int out_size, void* d_ws, size_t ws_size,
                              hipStream_t stream) {
  (void)in_sizes; (void)n_in; (void)out_size; (void)ws_size;
  const float* x        = (const float*)d_in[0];
  const float* m_ln_w   = (const float*)d_in[1];
  const float* m_Wup    = (const float*)d_in[2];
  const float* m_conv_w = (const float*)d_in[3];
  const float* m_conv_b = (const float*)d_in[4];
  const float* m_Wq     = (const float*)d_in[5];
  const float* m_Wk     = (const float*)d_in[6];
  const float* m_Wv     = (const float*)d_in[7];
  const float* m_Wig    = (const float*)d_in[8];
  const float* m_big    = (const float*)d_in[9];
  const float* m_Wfg    = (const float*)d_in[10];
  const float* m_bfg    = (const float*)d_in[11];
  const float* m_mhln_w = (const float*)d_in[12];
  const float* m_skip   = (const float*)d_in[13];
  const float* m_Wdown  = (const float*)d_in[14];
  const float* s_ln_w   = (const float*)d_in[15];
  const float* s_conv_w = (const float*)d_in[16];
  const float* s_conv_b = (const float*)d_in[17];
  const float* s_Wi     = (const float*)d_in[18];
  const float* s_Wf     = (const float*)d_in[19];
  const float* s_Wz     = (const float*)d_in[20];
  const float* s_Wo     = (const float*)d_in[21];
  const float* s_R      = (const float*)d_in[22];
  const float* s_b      = (const float*)d_in[23];
  const float* s_mhln_w = (const float*)d_in[24];
  const float* s_ffn_ln_w = (const float*)d_in[25];
  const float* s_Wup    = (const float*)d_in[26];
  const float* s_Wdown2 = (const float*)d_in[27];
  const float* post_ln_w = (const float*)d_in[28];
  const float* h_We     = (const float*)d_in[29];
  const float* h_be     = (const float*)d_in[30];
  const float* h_Ws     = (const float*)d_in[31];
  const float* h_bs     = (const float*)d_in[32];
  float* out = (float*)d_out;
  float* ws = (float*)d_ws;

  float* xn = ws + OFF_XN;
  float* up = ws + OFF_UP;
  float* xc = ws + OFF_XC;
  float* hsbuf = ws + OFF_HS;
  float* hb = ws + OFF_H;
  float* x1 = ws + OFF_X1;
  float* wqk_ig = ws + OFF_SM;
  float* wv_ig  = wqk_ig + 8192;
  float* wqk_fg = wqk_ig + 16384;
  float* wv_fg  = wqk_ig + 24576;
  float* igb    = ws + OFF_SM + 32768;
  float* fgb    = igb + 16384;
  float* lfcb   = igb + 32768;
  float* feat   = igb + 49152;

  // ---- block 0: mLSTM ----
  ln1024_kernel<<<4096, 256, 0, stream>>>(x, m_ln_w, xn, 0);
  gemm_kernel<false><<<dim3(32, 32, 1), 256, 0, stream>>>(
      xn, 1024, 0, m_Wup, 4096, 0, nullptr, 0, 0, up, 4096, 0, 4096, 4096, 1024);
  conv_silu_kernel<<<(4096 * 512) / 256, 256, 0, stream>>>(
      up, 4096, m_conv_w, m_conv_b, xc, 2048, 2048);
  wtilde_kernel<<<32, 256, 0, stream>>>(m_Wq, m_Wk, m_Wv, m_Wig, m_Wfg,
                                        wqk_ig, wv_ig, wqk_fg, wv_fg);
  igfg_kernel<<<4096, 256, 0, stream>>>(xc, up, wqk_ig, wv_ig, wqk_fg, wv_fg,
                                        m_big, m_bfg, igb, fgb);
  lfc_kernel<<<16, 1024, 0, stream>>>(fgb, lfcb);
  hv_inplace_kernel<<<8192, 256, 0, stream>>>(up, m_Wv);
  mlstm_attn_kernel<<<dim3(32, 16), 256, 0, stream>>>(
      xc, up, m_Wq, m_Wk, lfcb, igb, hb);
  mhgate_kernel<<<16384, 128, 0, stream>>>(hb, m_mhln_w, m_skip, xc, up);
  gemm_kernel<false><<<dim3(8, 32, 1), 256, 0, stream>>>(
      hb, 2048, 0, m_Wdown, 1024, 0, x, 1024, 0, x1, 1024, 0, 4096, 1024, 2048);

  // ---- block 1: sLSTM ----
  ln1024_kernel<<<4096, 256, 0, stream>>>(x1, s_ln_w, xn, 0);
  conv_silu_kernel<<<(4096 * 256) / 256, 256, 0, stream>>>(
      xn, 1024, s_conv_w, s_conv_b, xc, 1024, 1024);
  float* gi = up;
  float* gf = up + (4l << 20);
  float* gz = up + (8l << 20);
  float* go = up + (12l << 20);
  gemm_kernel<true><<<dim3(2, 32, 4), 256, 0, stream>>>(
      xc, 1024, 256, s_Wi, 256, 65536, nullptr, 0, 0, gi, 1024, 256, 4096, 256, 256);
  gemm_kernel<true><<<dim3(2, 32, 4), 256, 0, stream>>>(
      xc, 1024, 256, s_Wf, 256, 65536, nullptr, 0, 0, gf, 1024, 256, 4096, 256, 256);
  gemm_kernel<true><<<dim3(2, 32, 4), 256, 0, stream>>>(
      xn, 1024, 256, s_Wz, 256, 65536, nullptr, 0, 0, gz, 1024, 256, 4096, 256, 256);
  gemm_kernel<true><<<dim3(2, 32, 4), 256, 0, stream>>>(
      xn, 1024, 256, s_Wo, 256, 65536, nullptr, 0, 0, go, 1024, 256, 4096, 256, 256);
  // xn is dead until the FFN layernorm -> reuse it for the packed R (2 MB)
  uint4* Rpacked = (uint4*)xn;
  rpack_kernel<<<512, 256, 0, stream>>>(s_R, Rpacked);
  slstm_scan_kernel<<<16, 1024, 0, stream>>>(gi, gf, gz, go, Rpacked, s_b, hsbuf);
  mhres_kernel<<<16384, 64, 0, stream>>>(hsbuf, s_mhln_w, x1, hb);
  float* x2 = hb;

  // ---- FFN ----
  ln1024_kernel<<<4096, 256, 0, stream>>>(x2, s_ffn_ln_w, xn, 0);
  float* ffn = up;
  gemm_kernel<false><<<dim3(21, 32, 1), 256, 0, stream>>>(
      xn, 1024, 0, s_Wup, 2688, 0, nullptr, 0, 0, ffn, 2688, 0, 4096, 2688, 1024);
  geglu_kernel<<<(4096 * 1344) / 256, 256, 0, stream>>>(ffn);
  gemm_kernel<false><<<dim3(8, 32, 1), 256, 0, stream>>>(
      ffn, 2688, 0, s_Wdown2, 1024, 0, x2, 1024, 0, x1, 1024, 0, 4096, 1024, 1344);
  float* x3 = x1;

  // ---- post: LN + SELU + mean pool + heads ----
  ln1024_kernel<<<4096, 256, 0, stream>>>(x3, post_ln_w, xn, 1);
  colmean_kernel<<<16, 256, 0, stream>>>(xn, feat);
  head_kernel<<<40, 256, 0, stream>>>(feat, h_We, h_be, h_Ws, h_bs, out);
}

// Round 7
// 6994.667 us; speedup vs baseline: 2.9323x; 1.1439x over previous
//
#include <hip/hip_runtime.h>
#include <hip/hip_bf16.h>

// ============================================================================
// xLSTM audio model. B=4, S=1024, D=1024, INNER=2048, NH_M=4, DH_M=512,
// NH_S=4, DH_S=256, K(conv)=4, FF_UP=1344. N = B*S = 4096 tokens.
//
// R7: all five big GEMMs moved from fp32 VALU (no fp32 MFMA on CDNA4) to
// bf16 MFMA (mfma_f32_16x16x32_bf16, fp32 accumulate). fp32->bf16 conversion
// fused into LDS staging; A and B both staged [row][K] so fragment loads are
// single ds_read_b128; 16B-atom XOR swizzle keeps frag reads 2-lane/bank.
// Scan (4.55 ms, at per-CU L2 stream ceiling) unchanged from R6.
// ============================================================================

#define DEV_INLINE __device__ __forceinline__

constexpr long OFF_XN = 0;
constexpr long OFF_UP = 4l << 20;
constexpr long OFF_XC = 20l << 20;
constexpr long OFF_HS = 24l << 20;
constexpr long OFF_H  = 28l << 20;
constexpr long OFF_X1 = 36l << 20;
constexpr long OFF_SM = 40l << 20;

typedef _Float16 f16x2 __attribute__((ext_vector_type(2)));
typedef short bf16x8 __attribute__((ext_vector_type(8)));
typedef float f32x4 __attribute__((ext_vector_type(4)));

DEV_INLINE float wave_reduce_sum(float v) {
#pragma unroll
  for (int o = 32; o > 0; o >>= 1) v += __shfl_xor(v, o);
  return v;
}

DEV_INLINE float silu_f(float x) { return x / (1.f + expf(-x)); }
DEV_INLINE float selu_f(float x) {
  return 1.0507009873554805f * (x > 0.f ? x : 1.6732632423543772f * (expf(x) - 1.f));
}

DEV_INLINE unsigned short f2bf(float f) {  // round-to-nearest-even
  unsigned u = __float_as_uint(f);
  return (unsigned short)((u + 0x7fffu + ((u >> 16) & 1u)) >> 16);
}
DEV_INLINE unsigned pk2(float a, float b) {
  return (unsigned)f2bf(a) | ((unsigned)f2bf(b) << 16);
}

DEV_INLINE float dot2u(unsigned h2, unsigned r2, float c) {
#if __has_builtin(__builtin_amdgcn_fdot2)
  return __builtin_amdgcn_fdot2(__builtin_bit_cast(f16x2, h2),
                                __builtin_bit_cast(f16x2, r2), c, false);
#else
  const f16x2 a = __builtin_bit_cast(f16x2, h2);
  const f16x2 b = __builtin_bit_cast(f16x2, r2);
  return c + (float)a[0] * (float)b[0] + (float)a[1] * (float)b[1];
#endif
}

// ---------------------------------------------------------------------------
// LayerNorm over D=1024 (one row per block, 256 threads), optional SELU.
// ---------------------------------------------------------------------------
__global__ __launch_bounds__(256) void ln1024_kernel(
    const float* __restrict__ in, const float* __restrict__ w,
    float* __restrict__ out, int applySelu) {
  __shared__ float sred[8];
  const int n = blockIdx.x, t = threadIdx.x;
  const long base = (long)n * 1024 + t * 4;
  float4 v = *(const float4*)&in[base];
  float s = v.x + v.y + v.z + v.w;
  s = wave_reduce_sum(s);
  const int wid = t >> 6;
  if ((t & 63) == 0) sred[wid] = s;
  __syncthreads();
  const float mu = (sred[0] + sred[1] + sred[2] + sred[3]) * (1.f / 1024.f);
  float4 d;
  d.x = v.x - mu; d.y = v.y - mu; d.z = v.z - mu; d.w = v.w - mu;
  float sq = d.x * d.x + d.y * d.y + d.z * d.z + d.w * d.w;
  sq = wave_reduce_sum(sq);
  if ((t & 63) == 0) sred[4 + wid] = sq;
  __syncthreads();
  const float var = (sred[4] + sred[5] + sred[6] + sred[7]) * (1.f / 1024.f);
  const float rstd = rsqrtf(var + 1e-5f);
  const float4 w4 = *(const float4*)&w[t * 4];
  float4 o4;
  o4.x = d.x * rstd * w4.x; o4.y = d.y * rstd * w4.y;
  o4.z = d.z * rstd * w4.z; o4.w = d.w * rstd * w4.w;
  if (applySelu) {
    o4.x = selu_f(o4.x); o4.y = selu_f(o4.y); o4.z = selu_f(o4.z); o4.w = selu_f(o4.w);
  }
  *(float4*)&out[base] = o4;
}

// ---------------------------------------------------------------------------
// bf16 MFMA GEMM: C[m,n] = sum_k A[m,k]*B[k,n] (+ Res), fp32 in/out.
// 128x128 tile, BK=32, 256 threads = 4 waves (2x2 of 64x64).
// WT=false: W is (K,N) row-major. WT=true: W is (N,K). blockIdx.z batches.
// LDS: A and B both staged as [row][K] bf16 in 16B atoms with XOR swizzle
// idx16(r,kg)=r*4+(kg^(r&3)) -> fragment ds_read_b128 is 2-lane/bank (free).
// MFMA layouts (m89-verified): A/B lane l holds 8 elems, row/col=l&15,
// k=(l>>4)*8+j; C/D row=(l>>4)*4+i, col=l&15.
// ---------------------------------------------------------------------------
DEV_INLINE int idx16(int r, int kg) { return r * 4 + (kg ^ (r & 3)); }

template <bool WT>
__global__ __launch_bounds__(256) void gemm_mfma_kernel(
    const float* __restrict__ A, int lda, long aZ,
    const float* __restrict__ W, int ldw, long wZ,
    const float* __restrict__ Res, int ldr, long rZ,
    float* __restrict__ C, int ldc, long cZ, int Kd) {
  __shared__ __align__(16) short As[4096];  // 128 rows x 4 kg x 8 bf16
  __shared__ __align__(16) short Bs[4096];
  const int t = threadIdx.x;
  const int lane = t & 63, wv = t >> 6;
  const int wr = wv >> 1, wc = wv & 1;
  const int lr = lane & 15, lk = lane >> 4;
  const int bn = blockIdx.x * 128, bm = blockIdx.y * 128;
  A += (long)blockIdx.z * aZ;
  W += (long)blockIdx.z * wZ;
  C += (long)blockIdx.z * cZ;
  const float* Rp = Res ? Res + (long)blockIdx.z * rZ : nullptr;

  f32x4 acc[4][4];
#pragma unroll
  for (int i = 0; i < 4; ++i)
#pragma unroll
    for (int j = 0; j < 4; ++j) acc[i][j] = (f32x4){0.f, 0.f, 0.f, 0.f};

  const int ar = t >> 1, ah = t & 1;          // A/BT staging: row, K-half
  const int bk = t >> 3, bng = (t & 7) * 16;  // B (K,N) staging

  for (int k0 = 0; k0 < Kd; k0 += 32) {
    // ---- stage A (fp32 -> bf16) ----
    {
      const float* ap = &A[(long)(bm + ar) * lda + k0 + ah * 16];
      const float4 v0 = *(const float4*)&ap[0];
      const float4 v1 = *(const float4*)&ap[4];
      const float4 v2 = *(const float4*)&ap[8];
      const float4 v3 = *(const float4*)&ap[12];
      uint4 p0, p1;
      p0.x = pk2(v0.x, v0.y); p0.y = pk2(v0.z, v0.w);
      p0.z = pk2(v1.x, v1.y); p0.w = pk2(v1.z, v1.w);
      p1.x = pk2(v2.x, v2.y); p1.y = pk2(v2.z, v2.w);
      p1.z = pk2(v3.x, v3.y); p1.w = pk2(v3.z, v3.w);
      *(uint4*)&As[idx16(ar, ah * 2 + 0) * 8] = p0;
      *(uint4*)&As[idx16(ar, ah * 2 + 1) * 8] = p1;
    }
    // ---- stage B ----
    if (WT) {  // W (N,K): rows of N, contiguous K -> same pattern as A
      const float* wp = &W[(long)(bn + ar) * ldw + k0 + ah * 16];
      const float4 v0 = *(const float4*)&wp[0];
      const float4 v1 = *(const float4*)&wp[4];
      const float4 v2 = *(const float4*)&wp[8];
      const float4 v3 = *(const float4*)&wp[12];
      uint4 p0, p1;
      p0.x = pk2(v0.x, v0.y); p0.y = pk2(v0.z, v0.w);
      p0.z = pk2(v1.x, v1.y); p0.w = pk2(v1.z, v1.w);
      p1.x = pk2(v2.x, v2.y); p1.y = pk2(v2.z, v2.w);
      p1.z = pk2(v3.x, v3.y); p1.w = pk2(v3.z, v3.w);
      *(uint4*)&Bs[idx16(ar, ah * 2 + 0) * 8] = p0;
      *(uint4*)&Bs[idx16(ar, ah * 2 + 1) * 8] = p1;
    } else {  // W (K,N): coalesced along N, transposed scalar writes to LDS
      const float* wp = &W[(long)(k0 + bk) * ldw + bn + bng];
      const float4 v0 = *(const float4*)&wp[0];
      const float4 v1 = *(const float4*)&wp[4];
      const float4 v2 = *(const float4*)&wp[8];
      const float4 v3 = *(const float4*)&wp[12];
      const int kg = bk >> 3, ke = bk & 7;
      float vv[16];
      *(float4*)&vv[0] = v0; *(float4*)&vv[4] = v1;
      *(float4*)&vv[8] = v2; *(float4*)&vv[12] = v3;
#pragma unroll
      for (int j = 0; j < 16; ++j)
        Bs[idx16(bng + j, kg) * 8 + ke] = (short)f2bf(vv[j]);
    }
    __syncthreads();

    // ---- fragments + MFMA ----
    bf16x8 afr[4], bfr[4];
#pragma unroll
    for (int mi = 0; mi < 4; ++mi)
      afr[mi] = *(const bf16x8*)&As[idx16(wr * 64 + mi * 16 + lr, lk) * 8];
#pragma unroll
    for (int ni = 0; ni < 4; ++ni)
      bfr[ni] = *(const bf16x8*)&Bs[idx16(wc * 64 + ni * 16 + lr, lk) * 8];
#pragma unroll
    for (int mi = 0; mi < 4; ++mi)
#pragma unroll
      for (int ni = 0; ni < 4; ++ni)
        acc[mi][ni] = __builtin_amdgcn_mfma_f32_16x16x32_bf16(
            afr[mi], bfr[ni], acc[mi][ni], 0, 0, 0);
    __syncthreads();
  }

  // ---- epilogue: C = acc (+ Res) ----
#pragma unroll
  for (int mi = 0; mi < 4; ++mi) {
    const int row0 = bm + wr * 64 + mi * 16 + lk * 4;
#pragma unroll
    for (int i = 0; i < 4; ++i) {
      const long cb = (long)(row0 + i) * ldc;
      const long rb = Rp ? (long)(row0 + i) * ldr : 0;
#pragma unroll
      for (int ni = 0; ni < 4; ++ni) {
        const int col = bn + wc * 64 + ni * 16 + lr;
        float v = acc[mi][ni][i];
        if (Rp) v += Rp[rb + col];
        C[cb + col] = v;
      }
    }
  }
}

// ---------------------------------------------------------------------------
// Depthwise causal conv1d (K=4) + SiLU. One float4 channel-group per thread.
// ---------------------------------------------------------------------------
__global__ __launch_bounds__(256) void conv_silu_kernel(
    const float* __restrict__ in, int ld_in,
    const float* __restrict__ w, const float* __restrict__ bias,
    float* __restrict__ out, int ld_out, int C) {
  const int idx = blockIdx.x * 256 + threadIdx.x;
  const int gpr = C >> 2;
  const int n = idx / gpr;
  const int c = (idx - n * gpr) << 2;
  const int s = n & 1023;
  float4 acc = *(const float4*)&bias[c];
  const float* wc = &w[c * 4];
#pragma unroll
  for (int tap = 0; tap < 4; ++tap) {
    const int sp = s - 3 + tap;
    if (sp >= 0) {
      const float4 xv = *(const float4*)&in[(long)(n - 3 + tap) * ld_in + c];
      acc.x += xv.x * wc[0 + tap];
      acc.y += xv.y * wc[4 + tap];
      acc.z += xv.z * wc[8 + tap];
      acc.w += xv.w * wc[12 + tap];
    }
  }
  acc.x = silu_f(acc.x); acc.y = silu_f(acc.y);
  acc.z = silu_f(acc.z); acc.w = silu_f(acc.w);
  *(float4*)&out[(long)n * ld_out + c] = acc;
}

// ---------------------------------------------------------------------------
// Fold the 4x4 block-diagonal q/k/v maps into Wig/Wfg.
// ---------------------------------------------------------------------------
__global__ __launch_bounds__(256) void wtilde_kernel(
    const float* __restrict__ Wq, const float* __restrict__ Wk,
    const float* __restrict__ Wv, const float* __restrict__ Wig,
    const float* __restrict__ Wfg,
    float* __restrict__ wqk_ig, float* __restrict__ wv_ig,
    float* __restrict__ wqk_fg, float* __restrict__ wv_fg) {
  const int idx = blockIdx.x * 256 + threadIdx.x;  // 8192
  const int c = idx >> 2, hm = idx & 3;
  const int bk = c >> 2, i = c & 3;
  float sqk_i = 0, sv_i = 0, sqk_f = 0, sv_f = 0;
#pragma unroll
  for (int o = 0; o < 4; ++o) {
    const float wq = Wq[(bk * 4 + o) * 4 + i];
    const float wk = Wk[(bk * 4 + o) * 4 + i];
    const float wv = Wv[(bk * 4 + o) * 4 + i];
    const int rq = bk * 4 + o;
    sqk_i += wq * Wig[rq * 4 + hm] + wk * Wig[(2048 + rq) * 4 + hm];
    sv_i  += wv * Wig[(4096 + rq) * 4 + hm];
    sqk_f += wq * Wfg[rq * 4 + hm] + wk * Wfg[(2048 + rq) * 4 + hm];
    sv_f  += wv * Wfg[(4096 + rq) * 4 + hm];
  }
  wqk_ig[idx] = sqk_i; wv_ig[idx] = sv_i;
  wqk_fg[idx] = sqk_f; wv_fg[idx] = sv_f;
}

// ---------------------------------------------------------------------------
// ig/fg: per token, 8 dot products of length 4096 (xc part + xi part).
// ---------------------------------------------------------------------------
__global__ __launch_bounds__(256) void igfg_kernel(
    const float* __restrict__ xc, const float* __restrict__ up,
    const float* __restrict__ wqk_ig, const float* __restrict__ wv_ig,
    const float* __restrict__ wqk_fg, const float* __restrict__ wv_fg,
    const float* __restrict__ big, const float* __restrict__ bfg,
    float* __restrict__ ig, float* __restrict__ fg) {
  __shared__ float red[4][8];
  const int n = blockIdx.x, t = threadIdx.x;
  float ai[4] = {0, 0, 0, 0}, af[4] = {0, 0, 0, 0};
  for (int c = t; c < 2048; c += 256) {
    const float xcv = xc[(long)n * 2048 + c];
    const float xiv = up[(long)n * 4096 + c];
    const float4 wiq = *(const float4*)&wqk_ig[c * 4];
    const float4 wiv = *(const float4*)&wv_ig[c * 4];
    const float4 wfq = *(const float4*)&wqk_fg[c * 4];
    const float4 wfv = *(const float4*)&wv_fg[c * 4];
    ai[0] += xcv * wiq.x + xiv * wiv.x;
    ai[1] += xcv * wiq.y + xiv * wiv.y;
    ai[2] += xcv * wiq.z + xiv * wiv.z;
    ai[3] += xcv * wiq.w + xiv * wiv.w;
    af[0] += xcv * wfq.x + xiv * wfv.x;
    af[1] += xcv * wfq.y + xiv * wfv.y;
    af[2] += xcv * wfq.z + xiv * wfv.z;
    af[3] += xcv * wfq.w + xiv * wfv.w;
  }
#pragma unroll
  for (int j = 0; j < 4; ++j) {
    ai[j] = wave_reduce_sum(ai[j]);
    af[j] = wave_reduce_sum(af[j]);
  }
  const int wid = t >> 6;
  if ((t & 63) == 0) {
#pragma unroll
    for (int j = 0; j < 4; ++j) { red[wid][j] = ai[j]; red[wid][4 + j] = af[j]; }
  }
  __syncthreads();
  if (t < 8) {
    const float v = red[0][t] + red[1][t] + red[2][t] + red[3][t];
    const int b = n >> 10, s = n & 1023;
    if (t < 4) ig[((long)b * 4 + t) * 1024 + s] = v + big[t];
    else       fg[((long)b * 4 + (t - 4)) * 1024 + s] = v + bfg[t - 4];
  }
}

// ---------------------------------------------------------------------------
// lfc = cumsum(log_sigmoid(fg)) over S per (b,h). Hillis-Steele in LDS.
// ---------------------------------------------------------------------------
__global__ __launch_bounds__(1024) void lfc_kernel(
    const float* __restrict__ fg, float* __restrict__ lfc) {
  __shared__ float sh[1024];
  const int bh = blockIdx.x, t = threadIdx.x;
  const float x = fg[(long)bh * 1024 + t];
  sh[t] = fminf(x, 0.f) - log1pf(expf(-fabsf(x)));
  __syncthreads();
  for (int off = 1; off < 1024; off <<= 1) {
    const float add = (t >= off) ? sh[t - off] : 0.f;
    __syncthreads();
    sh[t] += add;
    __syncthreads();
  }
  lfc[(long)bh * 1024 + t] = sh[t];
}

// ---------------------------------------------------------------------------
// v = headwise(xi, Wv) in place over the xi region of `up`.
// ---------------------------------------------------------------------------
__global__ __launch_bounds__(256) void hv_inplace_kernel(
    float* __restrict__ up, const float* __restrict__ Wv) {
  const int idx = blockIdx.x * 256 + threadIdx.x;  // Ntok*512
  const int n = idx >> 9, bk = idx & 511;
  const long a = (long)n * 4096 + (bk << 2);
  const float4 xv = *(const float4*)&up[a];
  const float* wb = &Wv[bk << 4];
  float4 o;
  o.x = xv.x * wb[0]  + xv.y * wb[1]  + xv.z * wb[2]  + xv.w * wb[3];
  o.y = xv.x * wb[4]  + xv.y * wb[5]  + xv.z * wb[6]  + xv.w * wb[7];
  o.z = xv.x * wb[8]  + xv.y * wb[9]  + xv.z * wb[10] + xv.w * wb[11];
  o.w = xv.x * wb[12] + xv.y * wb[13] + xv.z * wb[14] + xv.w * wb[15];
  *(float4*)&up[a] = o;
}

// ---------------------------------------------------------------------------
// mLSTM parallel, flash-style. Grid (32 rowblocks, 16 bh), 256 threads.
// ---------------------------------------------------------------------------
__global__ __launch_bounds__(256) void mlstm_attn_kernel(
    const float* __restrict__ xc, const float* __restrict__ up,
    const float* __restrict__ Wq, const float* __restrict__ Wk,
    const float* __restrict__ lfc, const float* __restrict__ igv,
    float* __restrict__ hout) {
  __shared__ float q_s[32][516];
  __shared__ float kv_s[32][516];
  __shared__ float p_s[32][36];
  __shared__ float lfci_s[32], lfcj_s[32], igj_s[32];
  const int t = threadIdx.x;
  const int ti = t >> 5, tj = t & 31;
  const int i0 = blockIdx.x * 32;
  const int bh = blockIdx.y;
  const int b = bh >> 2, h = bh & 3;
  const float kscale = 0.04419417382415922f;  // 512^-0.5

  for (int idx = t; idx < 32 * 128; idx += 256) {
    const int r = idx >> 7, g = idx & 127;
    const float4 xv =
        *(const float4*)&xc[((long)(b * 1024 + i0 + r)) * 2048 + h * 512 + (g << 2)];
    const float* wb = Wq + ((h * 128 + g) << 4);
    float4 q4;
    q4.x = xv.x * wb[0]  + xv.y * wb[1]  + xv.z * wb[2]  + xv.w * wb[3];
    q4.y = xv.x * wb[4]  + xv.y * wb[5]  + xv.z * wb[6]  + xv.w * wb[7];
    q4.z = xv.x * wb[8]  + xv.y * wb[9]  + xv.z * wb[10] + xv.w * wb[11];
    q4.w = xv.x * wb[12] + xv.y * wb[13] + xv.z * wb[14] + xv.w * wb[15];
    *(float4*)&q_s[r][g << 2] = q4;
  }
  if (t < 32) lfci_s[t] = lfc[(long)bh * 1024 + i0 + t];

  const int r0 = ti * 4;
  float m_run[4], ssum[4], accv[4][16];
#pragma unroll
  for (int e = 0; e < 4; ++e) {
    m_run[e] = -INFINITY; ssum[e] = 0.f;
#pragma unroll
    for (int u = 0; u < 16; ++u) accv[e][u] = 0.f;
  }

  for (int j0 = 0; j0 <= i0; j0 += 32) {
    __syncthreads();
    for (int idx = t; idx < 32 * 128; idx += 256) {
      const int r = idx >> 7, g = idx & 127;
      const float4 xv =
          *(const float4*)&xc[((long)(b * 1024 + j0 + r)) * 2048 + h * 512 + (g << 2)];
      const float* wb = Wk + ((h * 128 + g) << 4);
      float4 k4;
      k4.x = (xv.x * wb[0]  + xv.y * wb[1]  + xv.z * wb[2]  + xv.w * wb[3])  * kscale;
      k4.y = (xv.x * wb[4]  + xv.y * wb[5]  + xv.z * wb[6]  + xv.w * wb[7])  * kscale;
      k4.z = (xv.x * wb[8]  + xv.y * wb[9]  + xv.z * wb[10] + xv.w * wb[11]) * kscale;
      k4.w = (xv.x * wb[12] + xv.y * wb[13] + xv.z * wb[14] + xv.w * wb[15]) * kscale;
      *(float4*)&kv_s[r][g << 2] = k4;
    }
    if (t < 32) {
      lfcj_s[t] = lfc[(long)bh * 1024 + j0 + t];
      igj_s[t] = igv[(long)bh * 1024 + j0 + t];
    }
    __syncthreads();

    float sv[4] = {0.f, 0.f, 0.f, 0.f};
#pragma unroll 2
    for (int d = 0; d < 512; d += 4) {
      const float4 kv = *(const float4*)&kv_s[tj][d];
#pragma unroll
      for (int e = 0; e < 4; ++e) {
        const float4 qv = *(const float4*)&q_s[r0 + e][d];
        sv[e] += qv.x * kv.x + qv.y * kv.y + qv.z * kv.z + qv.w * kv.w;
      }
    }
    const float lfcj = lfcj_s[tj], igj = igj_s[tj];
    float mt[4], logd[4];
    bool valid[4];
#pragma unroll
    for (int e = 0; e < 4; ++e) {
      valid[e] = (j0 + tj) <= (i0 + r0 + e);
      logd[e] = lfci_s[r0 + e] - lfcj + igj;
      mt[e] = valid[e] ? logd[e] : -INFINITY;
    }
#pragma unroll
    for (int o = 16; o > 0; o >>= 1) {
#pragma unroll
      for (int e = 0; e < 4; ++e) mt[e] = fmaxf(mt[e], __shfl_xor(mt[e], o));
    }
    float p[4];
#pragma unroll
    for (int e = 0; e < 4; ++e) {
      const float mn = fmaxf(m_run[e], mt[e]);
      const float scale = __expf(m_run[e] - mn);
      m_run[e] = mn;
      p[e] = valid[e] ? sv[e] * __expf(logd[e] - mn) : 0.f;
      float ps = p[e];
#pragma unroll
      for (int o = 16; o > 0; o >>= 1) ps += __shfl_xor(ps, o);
      ssum[e] = ssum[e] * scale + ps;
#pragma unroll
      for (int u = 0; u < 16; ++u) accv[e][u] *= scale;
      p_s[r0 + e][tj] = p[e];
    }
    __syncthreads();

    for (int idx = t; idx < 32 * 128; idx += 256) {
      const int r = idx >> 7, g = idx & 127;
      const float4 vv =
          *(const float4*)&up[((long)(b * 1024 + j0 + r)) * 4096 + h * 512 + (g << 2)];
      *(float4*)&kv_s[r][g << 2] = vv;
    }
    __syncthreads();

#pragma unroll 2
    for (int j = 0; j < 32; ++j) {
      const float pj0 = p_s[r0 + 0][j];
      const float pj1 = p_s[r0 + 1][j];
      const float pj2 = p_s[r0 + 2][j];
      const float pj3 = p_s[r0 + 3][j];
#pragma unroll
      for (int u = 0; u < 16; ++u) {
        const float vv = kv_s[j][tj + (u << 5)];
        accv[0][u] += pj0 * vv;
        accv[1][u] += pj1 * vv;
        accv[2][u] += pj2 * vv;
        accv[3][u] += pj3 * vv;
      }
    }
  }

#pragma unroll
  for (int e = 0; e < 4; ++e) {
    const float norm = fmaxf(fabsf(ssum[e]), __expf(-m_run[e]));
    const float inv = 1.f / (norm + 1e-6f);
    const long rowbase = ((long)(b * 1024 + i0 + r0 + e)) * 2048 + h * 512;
#pragma unroll
    for (int u = 0; u < 16; ++u) hout[rowbase + tj + (u << 5)] = accv[e][u] * inv;
  }
}

// ---------------------------------------------------------------------------
// Block-0 epilogue: per-head LN of h (DH=512), then (hn + skip*xc)*silu(z).
// ---------------------------------------------------------------------------
__global__ __launch_bounds__(128) void mhgate_kernel(
    float* __restrict__ hbuf, const float* __restrict__ mhw,
    const float* __restrict__ skip, const float* __restrict__ xc,
    const float* __restrict__ up) {
  __shared__ float sred[4];
  const int nh = blockIdx.x, t = threadIdx.x;
  const int n = nh >> 2, hd = nh & 3;
  const long base = (long)n * 2048 + hd * 512 + t * 4;
  const float4 v = *(const float4*)&hbuf[base];
  float s = wave_reduce_sum(v.x + v.y + v.z + v.w);
  if ((t & 63) == 0) sred[t >> 6] = s;
  __syncthreads();
  const float mu = (sred[0] + sred[1]) * (1.f / 512.f);
  float4 d;
  d.x = v.x - mu; d.y = v.y - mu; d.z = v.z - mu; d.w = v.w - mu;
  float sq = wave_reduce_sum(d.x * d.x + d.y * d.y + d.z * d.z + d.w * d.w);
  if ((t & 63) == 0) sred[2 + (t >> 6)] = sq;
  __syncthreads();
  const float rstd = rsqrtf((sred[2] + sred[3]) * (1.f / 512.f) + 1e-5f);
  const int ch = hd * 512 + t * 4;
  const float4 w4 = *(const float4*)&mhw[ch];
  const float4 sk4 = *(const float4*)&skip[ch];
  const float4 xc4 = *(const float4*)&xc[(long)n * 2048 + ch];
  const float4 z4 = *(const float4*)&up[(long)n * 4096 + 2048 + ch];
  float4 o;
  o.x = (d.x * rstd * w4.x + sk4.x * xc4.x) * silu_f(z4.x);
  o.y = (d.y * rstd * w4.y + sk4.y * xc4.y) * silu_f(z4.y);
  o.z = (d.z * rstd * w4.z + sk4.z * xc4.z) * silu_f(z4.z);
  o.w = (d.w * rstd * w4.w + sk4.w * xc4.w) * silu_f(z4.w);
  *(float4*)&hbuf[base] = o;
}

// ---------------------------------------------------------------------------
// Pack R (NH_S=4, 256 rows, 1024 cols fp32) -> f16 pairs: rows 8*d8..8*d8+7
// of column col in one uint4. Rp[(hd*32 + d8)*1024 + col].
// ---------------------------------------------------------------------------
__global__ __launch_bounds__(256) void rpack_kernel(
    const float* __restrict__ R, uint4* __restrict__ Rp) {
  const int idx = blockIdx.x * 256 + threadIdx.x;  // 131072
  const int hd = idx >> 15, rem = idx & 32767;
  const int d8 = rem >> 10, col = rem & 1023;
  const float* p = R + ((long)(hd * 256 + d8 * 8)) * 1024 + col;
  unsigned short hw[8];
#pragma unroll
  for (int k = 0; k < 8; ++k)
    hw[k] = __builtin_bit_cast(unsigned short, (_Float16)p[(long)k * 1024]);
  uint4 o;
  o.x = (unsigned)hw[0] | ((unsigned)hw[1] << 16);
  o.y = (unsigned)hw[2] | ((unsigned)hw[3] << 16);
  o.z = (unsigned)hw[4] | ((unsigned)hw[5] << 16);
  o.w = (unsigned)hw[6] | ((unsigned)hw[7] << 16);
  Rp[idx] = o;
}

// ---------------------------------------------------------------------------
// sLSTM sequential scan. One block (1024 threads) per (b,h). h f16-packed in
// LDS; R streamed as f16-pair uint4; v_dot2_f32_f16 MACs; gate preacts
// prefetched. At per-CU L2 stream ceiling (~115 GB/s/CU measured).
// ---------------------------------------------------------------------------
__global__ __launch_bounds__(1024) void slstm_scan_kernel(
    const float* __restrict__ gi, const float* __restrict__ gf,
    const float* __restrict__ gz, const float* __restrict__ go,
    const uint4* __restrict__ Rp, const float* __restrict__ bias,
    float* __restrict__ hsout) {
  __shared__ uint4 h16q[32];   // 256 f16 h values, packed
  __shared__ float ry[1024];
  const int t = threadIdx.x;
  const int b = blockIdx.x >> 2, hd = blockIdx.x & 3;
  const uint4* Rc = Rp + (long)hd * 32768 + t;  // [d8][col], stride 1024
  float c = 0.f, nn = 0.f, m = 0.f;
  float bi = 0, bf = 0, bz = 0, bo = 0;
  float gii = 0, gfv = 0, gzv = 0, gov = 0;
  if (t < 256) {
    ((_Float16*)h16q)[t] = (_Float16)0.f;
    bi = bias[(hd * 4 + 0) * 256 + t];
    bf = bias[(hd * 4 + 1) * 256 + t];
    bz = bias[(hd * 4 + 2) * 256 + t];
    bo = bias[(hd * 4 + 3) * 256 + t];
    const long pb0 = ((long)(b * 1024)) * 1024 + hd * 256 + t;
    gii = gi[pb0]; gfv = gf[pb0]; gzv = gz[pb0]; gov = go[pb0];
  }
  __syncthreads();
  for (int s = 0; s < 1024; ++s) {
    float acc = 0.f;
#pragma unroll 8
    for (int d8 = 0; d8 < 32; ++d8) {
      const uint4 rv = Rc[d8 * 1024];
      const uint4 hv = h16q[d8];
      acc = dot2u(hv.x, rv.x, acc);
      acc = dot2u(hv.y, rv.y, acc);
      acc = dot2u(hv.z, rv.z, acc);
      acc = dot2u(hv.w, rv.w, acc);
    }
    ry[t] = acc;
    float ni = 0, nf = 0, nz = 0, no = 0;
    if (t < 256 && s < 1023) {
      const long pb1 = ((long)(b * 1024 + s + 1)) * 1024 + hd * 256 + t;
      ni = gi[pb1]; nf = gf[pb1]; nz = gz[pb1]; no = go[pb1];
    }
    __syncthreads();
    if (t < 256) {
      const long pb = ((long)(b * 1024 + s)) * 1024 + hd * 256 + t;
      const float ir = gii + ry[t] + bi;
      const float fr = gfv + ry[256 + t] + bf;
      const float zr = gzv + ry[512 + t] + bz;
      const float og = gov + ry[768 + t] + bo;
      const float lsf = fminf(fr, 0.f) - log1pf(expf(-fabsf(fr)));
      const float lfm = m + lsf;
      const float mn = fmaxf(ir, lfm);
      const float igate = expf(ir - mn);
      const float fgate = expf(lfm - mn);
      c = fgate * c + igate * tanhf(zr);
      nn = fgate * nn + igate;
      const float hv = (1.f / (1.f + expf(-og))) * (c / (nn + 1e-6f));
      m = mn;
      ((_Float16*)h16q)[t] = (_Float16)hv;
      hsout[pb] = hv;
    }
    gii = ni; gfv = nf; gzv = nz; gov = no;
    __syncthreads();
  }
}

// ---------------------------------------------------------------------------
// sLSTM epilogue: x2 = x1 + mh_layernorm(hs) * w.
// ---------------------------------------------------------------------------
__global__ __launch_bounds__(64) void mhres_kernel(
    const float* __restrict__ hs, const float* __restrict__ w,
    const float* __restrict__ x1, float* __restrict__ x2) {
  const int nh = blockIdx.x, t = threadIdx.x;
  const int n = nh >> 2, hd = nh & 3;
  const long base = (long)n * 1024 + hd * 256 + t * 4;
  const float4 v = *(const float4*)&hs[base];
  const float mu = wave_reduce_sum(v.x + v.y + v.z + v.w) * (1.f / 256.f);
  float4 d;
  d.x = v.x - mu; d.y = v.y - mu; d.z = v.z - mu; d.w = v.w - mu;
  const float var =
      wave_reduce_sum(d.x * d.x + d.y * d.y + d.z * d.z + d.w * d.w) * (1.f / 256.f);
  const float rstd = rsqrtf(var + 1e-5f);
  const float4 w4 = *(const float4*)&w[hd * 256 + t * 4];
  const float4 r4 = *(const float4*)&x1[base];
  float4 o;
  o.x = r4.x + d.x * rstd * w4.x;
  o.y = r4.y + d.y * rstd * w4.y;
  o.z = r4.z + d.z * rstd * w4.z;
  o.w = r4.w + d.w * rstd * w4.w;
  *(float4*)&x2[base] = o;
}

// ---------------------------------------------------------------------------
// GeGLU (tanh-approx gelu), in place over g.
// ---------------------------------------------------------------------------
__global__ __launch_bounds__(256) void geglu_kernel(float* __restrict__ ffn) {
  const int idx = blockIdx.x * 256 + threadIdx.x;
  const int n = idx / 1344, j = idx % 1344;
  const long base = (long)n * 2688;
  const float g = ffn[base + j];
  const float u = ffn[base + 1344 + j];
  const float t3 = 0.7978845608028654f * (g + 0.044715f * g * g * g);
  ffn[base + j] = 0.5f * g * (1.f + tanhf(t3)) * u;
}

// ---------------------------------------------------------------------------
// Column mean over S.
// ---------------------------------------------------------------------------
__global__ __launch_bounds__(256) void colmean_kernel(
    const float* __restrict__ tmp, float* __restrict__ feat) {
  const int b = blockIdx.x >> 2;
  const int ch = ((blockIdx.x & 3) << 8) + threadIdx.x;
  const float* p = tmp + (long)b * 1024 * 1024 + ch;
  float s = 0.f;
#pragma unroll 4
  for (int si = 0; si < 1024; ++si) s += p[(long)si * 1024];
  feat[b * 1024 + ch] = s * (1.f / 1024.f);
}

// ---------------------------------------------------------------------------
// Classification heads.
// ---------------------------------------------------------------------------
__global__ __launch_bounds__(256) void head_kernel(
    const float* __restrict__ feat, const float* __restrict__ We,
    const float* __restrict__ be, const float* __restrict__ Ws,
    const float* __restrict__ bs, float* __restrict__ out) {
  __shared__ float sred[4];
  const int o = blockIdx.x, t = threadIdx.x;
  const int b = o / 10, j = o % 10;
  const float* wcol;
  int ld;
  float bias;
  if (j < 7) { wcol = We + j; ld = 7; bias = be[j]; }
  else       { wcol = Ws + (j - 7); ld = 3; bias = bs[j - 7]; }
  float s = 0.f;
  for (int d = t; d < 1024; d += 256) s += feat[b * 1024 + d] * wcol[d * ld];
  s = wave_reduce_sum(s);
  if ((t & 63) == 0) sred[t >> 6] = s;
  __syncthreads();
  if (t == 0) out[o] = sred[0] + sred[1] + sred[2] + sred[3] + bias;
}

// ===========================================================================
extern "C" void kernel_launch(void* const* d_in, const int* in_sizes, int n_in,
                              void* d_out, int out_size, void* d_ws, size_t ws_size,
                              hipStream_t stream) {
  (void)in_sizes; (void)n_in; (void)out_size; (void)ws_size;
  const float* x        = (const float*)d_in[0];
  const float* m_ln_w   = (const float*)d_in[1];
  const float* m_Wup    = (const float*)d_in[2];
  const float* m_conv_w = (const float*)d_in[3];
  const float* m_conv_b = (const float*)d_in[4];
  const float* m_Wq     = (const float*)d_in[5];
  const float* m_Wk     = (const float*)d_in[6];
  const float* m_Wv     = (const float*)d_in[7];
  const float* m_Wig    = (const float*)d_in[8];
  const float* m_big    = (const float*)d_in[9];
  const float* m_Wfg    = (const float*)d_in[10];
  const float* m_bfg    = (const float*)d_in[11];
  const float* m_mhln_w = (const float*)d_in[12];
  const float* m_skip   = (const float*)d_in[13];
  const float* m_Wdown  = (const float*)d_in[14];
  const float* s_ln_w   = (const float*)d_in[15];
  const float* s_conv_w = (const float*)d_in[16];
  const float* s_conv_b = (const float*)d_in[17];
  const float* s_Wi     = (const float*)d_in[18];
  const float* s_Wf     = (const float*)d_in[19];
  const float* s_Wz     = (const float*)d_in[20];
  const float* s_Wo     = (const float*)d_in[21];
  const float* s_R      = (const float*)d_in[22];
  const float* s_b      = (const float*)d_in[23];
  const float* s_mhln_w = (const float*)d_in[24];
  const float* s_ffn_ln_w = (const float*)d_in[25];
  const float* s_Wup    = (const float*)d_in[26];
  const float* s_Wdown2 = (const float*)d_in[27];
  const float* post_ln_w = (const float*)d_in[28];
  const float* h_We     = (const float*)d_in[29];
  const float* h_be     = (const float*)d_in[30];
  const float* h_Ws     = (const float*)d_in[31];
  const float* h_bs     = (const float*)d_in[32];
  float* out = (float*)d_out;
  float* ws = (float*)d_ws;

  float* xn = ws + OFF_XN;
  float* up = ws + OFF_UP;
  float* xc = ws + OFF_XC;
  float* hsbuf = ws + OFF_HS;
  float* hb = ws + OFF_H;
  float* x1 = ws + OFF_X1;
  float* wqk_ig = ws + OFF_SM;
  float* wv_ig  = wqk_ig + 8192;
  float* wqk_fg = wqk_ig + 16384;
  float* wv_fg  = wqk_ig + 24576;
  float* igb    = ws + OFF_SM + 32768;
  float* fgb    = igb + 16384;
  float* lfcb   = igb + 32768;
  float* feat   = igb + 49152;

  // ---- block 0: mLSTM ----
  ln1024_kernel<<<4096, 256, 0, stream>>>(x, m_ln_w, xn, 0);
  gemm_mfma_kernel<false><<<dim3(32, 32, 1), 256, 0, stream>>>(
      xn, 1024, 0, m_Wup, 4096, 0, nullptr, 0, 0, up, 4096, 0, 1024);
  conv_silu_kernel<<<(4096 * 512) / 256, 256, 0, stream>>>(
      up, 4096, m_conv_w, m_conv_b, xc, 2048, 2048);
  wtilde_kernel<<<32, 256, 0, stream>>>(m_Wq, m_Wk, m_Wv, m_Wig, m_Wfg,
                                        wqk_ig, wv_ig, wqk_fg, wv_fg);
  igfg_kernel<<<4096, 256, 0, stream>>>(xc, up, wqk_ig, wv_ig, wqk_fg, wv_fg,
                                        m_big, m_bfg, igb, fgb);
  lfc_kernel<<<16, 1024, 0, stream>>>(fgb, lfcb);
  hv_inplace_kernel<<<8192, 256, 0, stream>>>(up, m_Wv);
  mlstm_attn_kernel<<<dim3(32, 16), 256, 0, stream>>>(
      xc, up, m_Wq, m_Wk, lfcb, igb, hb);
  mhgate_kernel<<<16384, 128, 0, stream>>>(hb, m_mhln_w, m_skip, xc, up);
  gemm_mfma_kernel<false><<<dim3(8, 32, 1), 256, 0, stream>>>(
      hb, 2048, 0, m_Wdown, 1024, 0, x, 1024, 0, x1, 1024, 0, 2048);

  // ---- block 1: sLSTM ----
  ln1024_kernel<<<4096, 256, 0, stream>>>(x1, s_ln_w, xn, 0);
  conv_silu_kernel<<<(4096 * 256) / 256, 256, 0, stream>>>(
      xn, 1024, s_conv_w, s_conv_b, xc, 1024, 1024);
  float* gi = up;
  float* gf = up + (4l << 20);
  float* gz = up + (8l << 20);
  float* go = up + (12l << 20);
  gemm_mfma_kernel<true><<<dim3(2, 32, 4), 256, 0, stream>>>(
      xc, 1024, 256, s_Wi, 256, 65536, nullptr, 0, 0, gi, 1024, 256, 256);
  gemm_mfma_kernel<true><<<dim3(2, 32, 4), 256, 0, stream>>>(
      xc, 1024, 256, s_Wf, 256, 65536, nullptr, 0, 0, gf, 1024, 256, 256);
  gemm_mfma_kernel<true><<<dim3(2, 32, 4), 256, 0, stream>>>(
      xn, 1024, 256, s_Wz, 256, 65536, nullptr, 0, 0, gz, 1024, 256, 256);
  gemm_mfma_kernel<true><<<dim3(2, 32, 4), 256, 0, stream>>>(
      xn, 1024, 256, s_Wo, 256, 65536, nullptr, 0, 0, go, 1024, 256, 256);
  // xn is dead until the FFN layernorm -> reuse it for the packed R (2 MB)
  uint4* Rpacked = (uint4*)xn;
  rpack_kernel<<<512, 256, 0, stream>>>(s_R, Rpacked);
  slstm_scan_kernel<<<16, 1024, 0, stream>>>(gi, gf, gz, go, Rpacked, s_b, hsbuf);
  mhres_kernel<<<16384, 64, 0, stream>>>(hsbuf, s_mhln_w, x1, hb);
  float* x2 = hb;

  // ---- FFN ----
  ln1024_kernel<<<4096, 256, 0, stream>>>(x2, s_ffn_ln_w, xn, 0);
  float* ffn = up;
  gemm_mfma_kernel<false><<<dim3(21, 32, 1), 256, 0, stream>>>(
      xn, 1024, 0, s_Wup, 2688, 0, nullptr, 0, 0, ffn, 2688, 0, 1024);
  geglu_kernel<<<(4096 * 1344) / 256, 256, 0, stream>>>(ffn);
  gemm_mfma_kernel<false><<<dim3(8, 32, 1), 256, 0, stream>>>(
      ffn, 2688, 0, s_Wdown2, 1024, 0, x2, 1024, 0, x1, 1024, 0, 1344);
  float* x3 = x1;

  // ---- post: LN + SELU + mean pool + heads ----
  ln1024_kernel<<<4096, 256, 0, stream>>>(x3, post_ln_w, xn, 1);
  colmean_kernel<<<16, 256, 0, stream>>>(xn, feat);
  head_kernel<<<40, 256, 0, stream>>>(feat, h_We, h_be, h_Ws, h_bs, out);
}